// Round 1
// baseline (8539.195 us; speedup 1.0000x reference)
//
#include <hip/hip_runtime.h>
#include <math.h>

static constexpr int H    = 128;
static constexpr int MID  = 64;
static constexpr int NHD  = 8;   // heads
static constexpr int HD   = 16;  // head dim
static constexpr int NS   = 20000;
static constexpr int NT   = 20000;
static constexpr int EDG  = 320000;
static constexpr int SPH  = 12;  // 3*2^2
static constexpr int TOR  = 6;   // 3*2
static constexpr int TS   = 132; // LDS row stride (floats)

__device__ __forceinline__ float sil(float x) {
  return x / (1.0f + __expf(-x));
}

// acc[32] += sum_i xr[i] * W[i*ldw + j]   (W pre-offset by column base; uniform -> s_load)
template<int K>
__device__ __forceinline__ void kloop32(const float* __restrict__ W, int ldw,
                                        const float* xr, float* acc) {
  #pragma unroll 2
  for (int i0 = 0; i0 < K; i0 += 4) {
    float4 a4 = *(const float4*)(xr + i0);
    const float* w = W + i0 * ldw;
    #pragma unroll
    for (int j = 0; j < 32; ++j) acc[j] = fmaf(a4.x, w[j], acc[j]);
    w += ldw;
    #pragma unroll
    for (int j = 0; j < 32; ++j) acc[j] = fmaf(a4.y, w[j], acc[j]);
    w += ldw;
    #pragma unroll
    for (int j = 0; j < 32; ++j) acc[j] = fmaf(a4.z, w[j], acc[j]);
    w += ldw;
    #pragma unroll
    for (int j = 0; j < 32; ++j) acc[j] = fmaf(a4.w, w[j], acc[j]);
  }
}

// dual version: two weight bases, shared activation
template<int K>
__device__ __forceinline__ void kloop32x2(const float* __restrict__ Wa,
                                          const float* __restrict__ Wb, int ldw,
                                          const float* xr, float* acca, float* accb) {
  #pragma unroll 2
  for (int i0 = 0; i0 < K; i0 += 4) {
    float4 a4 = *(const float4*)(xr + i0);
    float av[4] = {a4.x, a4.y, a4.z, a4.w};
    #pragma unroll
    for (int u = 0; u < 4; ++u) {
      const float* wa = Wa + (i0 + u) * ldw;
      const float* wb = Wb + (i0 + u) * ldw;
      #pragma unroll
      for (int j = 0; j < 32; ++j) acca[j] = fmaf(av[u], wa[j], acca[j]);
      #pragma unroll
      for (int j = 0; j < 32; ++j) accb[j] = fmaf(av[u], wb[j], accb[j]);
    }
  }
}

// ---------------- tiny: Wsphe = Ws1@Ws2 (12x128), Wtors = Wt1@Wt2 (6x128) ----------------
__global__ void k_smallw(const float* __restrict__ Ws1, const float* __restrict__ Ws2,
                         const float* __restrict__ Wt1, const float* __restrict__ Wt2,
                         float* __restrict__ Wsphe, float* __restrict__ Wtors) {
  int tid = threadIdx.x;
  for (int o = tid; o < SPH * H; o += 256) {
    int i = o >> 7, c = o & 127;
    float acc = 0.f;
    for (int m = 0; m < MID; ++m) acc = fmaf(Ws1[i * MID + m], Ws2[m * H + c], acc);
    Wsphe[o] = acc;
  }
  for (int o = tid; o < TOR * H; o += 256) {
    int i = o >> 7, c = o & 127;
    float acc = 0.f;
    for (int m = 0; m < MID; ++m) acc = fmaf(Wt1[i * MID + m], Wt2[m * H + c], acc);
    Wtors[o] = acc;
  }
}

// ---------------- node GEMM: Out(M x128) = A(M x128) @ W(128x128) + b ----------------
__global__ __launch_bounds__(256, 4)
void k_gemm128(const float* __restrict__ A, const float* __restrict__ W,
               const float* __restrict__ bias, float* __restrict__ Out, int M) {
  __shared__ float X[64 * TS];
  int tid = threadIdx.x;
  int r0 = blockIdx.x * 64;
  for (int idx = tid; idx < 64 * 32; idx += 256) {
    int r = idx >> 5, seg = idx & 31;
    int row = r0 + r;
    float4 val = make_float4(0.f, 0.f, 0.f, 0.f);
    if (row < M) val = *(const float4*)(A + row * H + seg * 4);
    *(float4*)(X + r * TS + seg * 4) = val;
  }
  __syncthreads();
  int lane = tid & 63, wave = tid >> 6;
  int c0 = __builtin_amdgcn_readfirstlane(wave * 32);
  float acc[32];
  #pragma unroll
  for (int j = 0; j < 32; ++j) acc[j] = bias[c0 + j];
  kloop32<128>(W + c0, H, X + lane * TS, acc);
  int row = r0 + lane;
  if (row < M) {
    #pragma unroll
    for (int j4 = 0; j4 < 8; ++j4) {
      float4 o4 = make_float4(acc[j4*4], acc[j4*4+1], acc[j4*4+2], acc[j4*4+3]);
      *(float4*)(Out + row * H + c0 + j4 * 4) = o4;
    }
  }
}

// ---------------- edge kernel A: dk/dv -> attn -> v_j -> s -> atomics ----------------
__global__ __launch_bounds__(256, 4)
void k_edge_attn(const float* __restrict__ edge_attr, const int* __restrict__ ei,
                 const float* __restrict__ sphe, const float* __restrict__ tors,
                 const float* __restrict__ dist,
                 const float* __restrict__ q, const float* __restrict__ kk,
                 const float* __restrict__ vv,
                 const float* __restrict__ Wdk, const float* __restrict__ bdk,
                 const float* __restrict__ Wdv, const float* __restrict__ bdv,
                 const float* __restrict__ Wo_att, const float* __restrict__ bo_att,
                 const float* __restrict__ Ws_msg, const float* __restrict__ bs_msg,
                 const float* __restrict__ Wsphe, const float* __restrict__ Wtors,
                 float* __restrict__ s_msg, float* __restrict__ dsum) {
  __shared__ float X[64 * TS];
  int tid = threadIdx.x;
  int e0 = blockIdx.x * 64;
  for (int idx = tid; idx < 64 * 32; idx += 256) {
    int r = idx >> 5, seg = idx & 31;
    *(float4*)(X + r * TS + seg * 4) = *(const float4*)(edge_attr + (e0 + r) * H + seg * 4);
  }
  __syncthreads();
  int lane = tid & 63, wave = tid >> 6;
  int c0 = __builtin_amdgcn_readfirstlane(wave * 32);
  int e = e0 + lane;
  int s = ei[e];
  int t = ei[EDG + e];
  const float* xr = X + lane * TS;

  // phase 1: dk, dv = silu(ea @ W + b)
  float dk[32], dv[32];
  #pragma unroll
  for (int j = 0; j < 32; ++j) { dk[j] = bdk[c0 + j]; dv[j] = bdv[c0 + j]; }
  kloop32x2<128>(Wdk + c0, Wdv + c0, H, xr, dk, dv);
  #pragma unroll
  for (int j = 0; j < 32; ++j) { dk[j] = sil(dk[j]); dv[j] = sil(dv[j]); }

  // attn for this wave's two heads
  float ah0 = 0.f, ah1 = 0.f;
  #pragma unroll
  for (int j8 = 0; j8 < 8; ++j8) {
    float4 q4 = *(const float4*)(q  + t * H + c0 + j8 * 4);
    float4 k4 = *(const float4*)(kk + s * H + c0 + j8 * 4);
    float p = q4.x * k4.x * dk[j8*4]   + q4.y * k4.y * dk[j8*4+1]
            + q4.z * k4.z * dk[j8*4+2] + q4.w * k4.w * dk[j8*4+3];
    if (j8 < 4) ah0 += p; else ah1 += p;
  }
  float dd = dist[e];
  float cutv = (dd < 5.0f) ? 0.5f * (__cosf(0.6283185307179586f * dd) + 1.0f) : 0.0f;
  float a0 = sil(ah0) * cutv;
  float a1 = sil(ah1) * cutv;

  // vjpre = v[src] * dv * attn
  float vj[32];
  #pragma unroll
  for (int j8 = 0; j8 < 8; ++j8) {
    float4 v4 = *(const float4*)(vv + s * H + c0 + j8 * 4);
    float aa = (j8 < 4) ? a0 : a1;
    vj[j8*4]   = v4.x * dv[j8*4]   * aa;
    vj[j8*4+1] = v4.y * dv[j8*4+1] * aa;
    vj[j8*4+2] = v4.z * dv[j8*4+2] * aa;
    vj[j8*4+3] = v4.w * dv[j8*4+3] * aa;
  }
  __syncthreads();          // everyone done reading ea
  #pragma unroll
  for (int j4 = 0; j4 < 8; ++j4) {
    float4 o4 = make_float4(vj[j4*4], vj[j4*4+1], vj[j4*4+2], vj[j4*4+3]);
    *(float4*)(X + lane * TS + c0 + j4 * 4) = o4;
  }
  __syncthreads();

  // phase 2: v_j = silu(vjpre @ Wo_att + b)
  float acc[32];
  #pragma unroll
  for (int j = 0; j < 32; ++j) acc[j] = bo_att[c0 + j];
  kloop32<128>(Wo_att + c0, H, xr, acc);
  #pragma unroll
  for (int j = 0; j < 32; ++j) vj[j] = sil(acc[j]);
  #pragma unroll
  for (int j = 0; j < 32; ++j) atomicAdd(&s_msg[t * H + c0 + j], vj[j]);
  __syncthreads();          // everyone done reading vjpre
  #pragma unroll
  for (int j4 = 0; j4 < 8; ++j4) {
    float4 o4 = make_float4(vj[j4*4], vj[j4*4+1], vj[j4*4+2], vj[j4*4+3]);
    *(float4*)(X + lane * TS + c0 + j4 * 4) = o4;
  }
  __syncthreads();

  // phase 3: s = silu(v_j @ Ws_msg + b), cols c1..c1+63; d_ji atomics
  int c1 = __builtin_amdgcn_readfirstlane(wave * 64);
  float s0[32], s1[32];
  #pragma unroll
  for (int j = 0; j < 32; ++j) { s0[j] = bs_msg[c1 + j]; s1[j] = bs_msg[c1 + 32 + j]; }
  kloop32x2<128>(Ws_msg + c1, Ws_msg + c1 + 32, 2 * H, xr, s0, s1);
  #pragma unroll
  for (int j = 0; j < 32; ++j) { s0[j] = sil(s0[j]); s1[j] = sil(s1[j]); }

  if (wave < 2) {
    const float4* spp = (const float4*)(sphe + e * SPH);
    float4 sa = spp[0], sb = spp[1], sc = spp[2];
    float sp[12] = {sa.x, sa.y, sa.z, sa.w, sb.x, sb.y, sb.z, sb.w, sc.x, sc.y, sc.z, sc.w};
    #pragma unroll
    for (int j = 0; j < 32; ++j) {
      float d = 0.f;
      #pragma unroll
      for (int i = 0; i < 12; ++i) d = fmaf(sp[i], Wsphe[i * H + c1 + j], d);
      atomicAdd(&dsum[t * 2 * H + c1 + j], s0[j] * d);
    }
    #pragma unroll
    for (int j = 0; j < 32; ++j) {
      float d = 0.f;
      #pragma unroll
      for (int i = 0; i < 12; ++i) d = fmaf(sp[i], Wsphe[i * H + c1 + 32 + j], d);
      atomicAdd(&dsum[t * 2 * H + c1 + 32 + j], s1[j] * d);
    }
  } else {
    const float* tpp = tors + e * TOR;
    float tp[6];
    #pragma unroll
    for (int i = 0; i < 6; ++i) tp[i] = tpp[i];
    int d0 = c1 - 128;
    #pragma unroll
    for (int j = 0; j < 32; ++j) {
      float d = 0.f;
      #pragma unroll
      for (int i = 0; i < 6; ++i) d = fmaf(tp[i], Wtors[i * H + d0 + j], d);
      atomicAdd(&dsum[t * 2 * H + c1 + j], s0[j] * d);
    }
    #pragma unroll
    for (int j = 0; j < 32; ++j) {
      float d = 0.f;
      #pragma unroll
      for (int i = 0; i < 6; ++i) d = fmaf(tp[i], Wtors[i * H + d0 + 32 + j], d);
      atomicAdd(&dsum[t * 2 * H + c1 + 32 + j], s1[j] * d);
    }
  }
}

// ---------------- edge kernel B: f path -> f_ji ----------------
__global__ __launch_bounds__(256, 2)
void k_edge_f(const float* __restrict__ edge_attr,
              const float* __restrict__ sphe, const float* __restrict__ tors,
              const float* __restrict__ Wf, const float* __restrict__ bf,
              const float* __restrict__ Wcat_f, const float* __restrict__ bcat_f,
              const float* __restrict__ Wsphe, const float* __restrict__ Wtors,
              float* __restrict__ out_fji) {
  __shared__ float X[64 * TS];
  __shared__ float Y[64 * TS];
  int tid = threadIdx.x;
  int e0 = blockIdx.x * 64;
  for (int idx = tid; idx < 64 * 32; idx += 256) {
    int r = idx >> 5, seg = idx & 31;
    *(float4*)(X + r * TS + seg * 4) = *(const float4*)(edge_attr + (e0 + r) * H + seg * 4);
  }
  __syncthreads();
  int lane = tid & 63, wave = tid >> 6;
  int c0 = __builtin_amdgcn_readfirstlane(wave * 32);
  int e = e0 + lane;
  const float* xr = X + lane * TS;
  const float* yr = Y + lane * TS;

  const float4* spp = (const float4*)(sphe + e * SPH);
  float4 sa = spp[0], sb = spp[1], sc = spp[2];
  float sp[12] = {sa.x, sa.y, sa.z, sa.w, sb.x, sb.y, sb.z, sb.w, sc.x, sc.y, sc.z, sc.w};
  const float* tpp = tors + e * TOR;
  float tp[6];
  #pragma unroll
  for (int i = 0; i < 6; ++i) tp[i] = tpp[i];

  // phase 1: f2 = silu(ea @ Wf[:,128:256] + b), y = f2 * d1
  float acc[32];
  #pragma unroll
  for (int j = 0; j < 32; ++j) acc[j] = bf[H + c0 + j];
  kloop32<128>(Wf + H + c0, 3 * H, xr, acc);
  #pragma unroll
  for (int j = 0; j < 32; ++j) {
    float d = 0.f;
    #pragma unroll
    for (int i = 0; i < 12; ++i) d = fmaf(sp[i], Wsphe[i * H + c0 + j], d);
    acc[j] = sil(acc[j]) * d;
  }
  #pragma unroll
  for (int j4 = 0; j4 < 8; ++j4) {
    float4 o4 = make_float4(acc[j4*4], acc[j4*4+1], acc[j4*4+2], acc[j4*4+3]);
    *(float4*)(Y + lane * TS + c0 + j4 * 4) = o4;
  }
  __syncthreads();

  // phase 2: acco = y @ Wcat_f[0:128]
  float acco[32];
  #pragma unroll
  for (int j = 0; j < 32; ++j) acco[j] = 0.f;
  kloop32<128>(Wcat_f + c0, H, yr, acco);
  __syncthreads();

  // phase 3: f3 = silu(ea @ Wf[:,256:384] + b), y = f3 * d2
  #pragma unroll
  for (int j = 0; j < 32; ++j) acc[j] = bf[2 * H + c0 + j];
  kloop32<128>(Wf + 2 * H + c0, 3 * H, xr, acc);
  #pragma unroll
  for (int j = 0; j < 32; ++j) {
    float d = 0.f;
    #pragma unroll
    for (int i = 0; i < 6; ++i) d = fmaf(tp[i], Wtors[i * H + c0 + j], d);
    acc[j] = sil(acc[j]) * d;
  }
  #pragma unroll
  for (int j4 = 0; j4 < 8; ++j4) {
    float4 o4 = make_float4(acc[j4*4], acc[j4*4+1], acc[j4*4+2], acc[j4*4+3]);
    *(float4*)(Y + lane * TS + c0 + j4 * 4) = o4;
  }
  __syncthreads();

  // phase 4: acco += y @ Wcat_f[128:256]
  kloop32<128>(Wcat_f + H * H + c0, H, yr, acco);

  // phase 5: f1 = silu(ea @ Wf[:,0:128] + b); out = f1 + silu(acco + bcat)
  #pragma unroll
  for (int j = 0; j < 32; ++j) acc[j] = bf[c0 + j];
  kloop32<128>(Wf + c0, 3 * H, xr, acc);
  #pragma unroll
  for (int j = 0; j < 32; ++j) acc[j] = sil(acc[j]) + sil(acco[j] + bcat_f[c0 + j]);
  #pragma unroll
  for (int j4 = 0; j4 < 8; ++j4) {
    float4 o4 = make_float4(acc[j4*4], acc[j4*4+1], acc[j4*4+2], acc[j4*4+3]);
    *(float4*)(out_fji + e * H + c0 + j4 * 4) = o4;
  }
}

// ---------------- d_msg = dsum @ Wcat_msg  (M=NT, K=256, N=128) ----------------
__global__ __launch_bounds__(256, 2)
void k_dmsg(const float* __restrict__ dsum, const float* __restrict__ Wcat_msg,
            float* __restrict__ d_msg) {
  __shared__ float X[64 * 260];
  int tid = threadIdx.x;
  int r0 = blockIdx.x * 64;
  for (int idx = tid; idx < 64 * 64; idx += 256) {
    int r = idx >> 6, seg = idx & 63;
    int row = r0 + r;
    float4 val = make_float4(0.f, 0.f, 0.f, 0.f);
    if (row < NT) val = *(const float4*)(dsum + row * 2 * H + seg * 4);
    *(float4*)(X + r * 260 + seg * 4) = val;
  }
  __syncthreads();
  int lane = tid & 63, wave = tid >> 6;
  int c0 = __builtin_amdgcn_readfirstlane(wave * 32);
  float acc[32];
  #pragma unroll
  for (int j = 0; j < 32; ++j) acc[j] = 0.f;
  kloop32<256>(Wcat_msg + c0, H, X + lane * 260, acc);
  int row = r0 + lane;
  if (row < NT) {
    #pragma unroll
    for (int j4 = 0; j4 < 8; ++j4) {
      float4 o4 = make_float4(acc[j4*4], acc[j4*4+1], acc[j4*4+2], acc[j4*4+3]);
      *(float4*)(d_msg + row * H + c0 + j4 * 4) = o4;
    }
  }
}

// ---------------- final: o = s_msg@Wo_msg+b; z = o1 + o2*d_msg; h = silu([x_t,z]@Wfinal+b) ----------------
__global__ __launch_bounds__(256, 2)
void k_final(const float* __restrict__ s_msg, const float* __restrict__ x_t,
             const float* __restrict__ d_msg,
             const float* __restrict__ Wo_msg, const float* __restrict__ bo_msg,
             const float* __restrict__ Wfinal, const float* __restrict__ bfinal,
             float* __restrict__ out_ht) {
  __shared__ float SM[64 * TS];
  __shared__ float XT[64 * TS];
  int tid = threadIdx.x;
  int r0 = blockIdx.x * 64;
  for (int idx = tid; idx < 64 * 32; idx += 256) {
    int r = idx >> 5, seg = idx & 31;
    int row = r0 + r;
    float4 v1 = make_float4(0.f, 0.f, 0.f, 0.f), v2 = v1;
    if (row < NT) {
      v1 = *(const float4*)(s_msg + row * H + seg * 4);
      v2 = *(const float4*)(x_t   + row * H + seg * 4);
    }
    *(float4*)(SM + r * TS + seg * 4) = v1;
    *(float4*)(XT + r * TS + seg * 4) = v2;
  }
  __syncthreads();
  int lane = tid & 63, wave = tid >> 6;
  int c0 = __builtin_amdgcn_readfirstlane(wave * 32);
  int row = r0 + lane;
  float acc1[32], acc2[32];
  #pragma unroll
  for (int j = 0; j < 32; ++j) { acc1[j] = bo_msg[c0 + j]; acc2[j] = bo_msg[H + c0 + j]; }
  kloop32x2<128>(Wo_msg + c0, Wo_msg + H + c0, 2 * H, SM + lane * TS, acc1, acc2);
  // z = o1 + o2 * d_msg
  float z[32];
  if (row < NT) {
    #pragma unroll
    for (int j4 = 0; j4 < 8; ++j4) {
      float4 dm = *(const float4*)(d_msg + row * H + c0 + j4 * 4);
      z[j4*4]   = acc1[j4*4]   + acc2[j4*4]   * dm.x;
      z[j4*4+1] = acc1[j4*4+1] + acc2[j4*4+1] * dm.y;
      z[j4*4+2] = acc1[j4*4+2] + acc2[j4*4+2] * dm.z;
      z[j4*4+3] = acc1[j4*4+3] + acc2[j4*4+3] * dm.w;
    }
  } else {
    #pragma unroll
    for (int j = 0; j < 32; ++j) z[j] = 0.f;
  }
  __syncthreads();
  #pragma unroll
  for (int j4 = 0; j4 < 8; ++j4) {
    float4 o4 = make_float4(z[j4*4], z[j4*4+1], z[j4*4+2], z[j4*4+3]);
    *(float4*)(SM + lane * TS + c0 + j4 * 4) = o4;
  }
  __syncthreads();
  float acc[32];
  #pragma unroll
  for (int j = 0; j < 32; ++j) acc[j] = bfinal[c0 + j];
  kloop32<128>(Wfinal + c0, H, XT + lane * TS, acc);             // x_t part (rows 0..127)
  kloop32<128>(Wfinal + H * H + c0, H, SM + lane * TS, acc);     // z part (rows 128..255)
  if (row < NT) {
    #pragma unroll
    for (int j4 = 0; j4 < 8; ++j4) {
      float4 o4 = make_float4(sil(acc[j4*4]), sil(acc[j4*4+1]), sil(acc[j4*4+2]), sil(acc[j4*4+3]));
      *(float4*)(out_ht + row * H + c0 + j4 * 4) = o4;
    }
  }
}

extern "C" void kernel_launch(void* const* d_in, const int* in_sizes, int n_in,
                              void* d_out, int out_size, void* d_ws, size_t ws_size,
                              hipStream_t stream) {
  const float* x_s       = (const float*)d_in[0];
  const float* x_t       = (const float*)d_in[1];
  const int*   ei        = (const int*)  d_in[2];
  const float* edge_attr = (const float*)d_in[3];
  const float* sphe      = (const float*)d_in[4];
  const float* tors      = (const float*)d_in[5];
  const float* dist      = (const float*)d_in[6];
  const float* Ws1       = (const float*)d_in[7];
  const float* Ws2       = (const float*)d_in[8];
  const float* Wt1       = (const float*)d_in[9];
  const float* Wt2       = (const float*)d_in[10];
  const float* Wq        = (const float*)d_in[11];
  const float* bq        = (const float*)d_in[12];
  const float* Wk        = (const float*)d_in[13];
  const float* bk        = (const float*)d_in[14];
  const float* Wv        = (const float*)d_in[15];
  const float* bv        = (const float*)d_in[16];
  const float* Wdk       = (const float*)d_in[17];
  const float* bdk       = (const float*)d_in[18];
  const float* Wdv       = (const float*)d_in[19];
  const float* bdv       = (const float*)d_in[20];
  const float* Wo_att    = (const float*)d_in[21];
  const float* bo_att    = (const float*)d_in[22];
  const float* Ws_msg    = (const float*)d_in[23];
  const float* bs_msg    = (const float*)d_in[24];
  const float* Wcat_msg  = (const float*)d_in[25];
  const float* Wo_msg    = (const float*)d_in[26];
  const float* bo_msg    = (const float*)d_in[27];
  const float* Wfinal    = (const float*)d_in[28];
  const float* bfinal    = (const float*)d_in[29];
  const float* Wf        = (const float*)d_in[30];
  const float* bf        = (const float*)d_in[31];
  const float* Wcat_f    = (const float*)d_in[32];
  const float* bcat_f    = (const float*)d_in[33];

  float* ws = (float*)d_ws;
  float* qbuf  = ws;                       // NT*H
  float* kbuf  = qbuf  + (size_t)NT * H;   // NS*H
  float* vbuf  = kbuf  + (size_t)NS * H;   // NS*H
  float* smsg  = vbuf  + (size_t)NS * H;   // NT*H
  float* dsum  = smsg  + (size_t)NT * H;   // NT*2H
  float* dmsg  = dsum  + (size_t)NT * 2 * H; // NT*H
  float* wsphe = dmsg  + (size_t)NT * H;   // 12*128
  float* wtors = wsphe + SPH * H;          // 6*128

  float* out_ht  = (float*)d_out;
  float* out_fji = out_ht + (size_t)NT * H;

  hipMemsetAsync(smsg, 0, (size_t)NT * H * sizeof(float), stream);
  hipMemsetAsync(dsum, 0, (size_t)NT * 2 * H * sizeof(float), stream);

  k_smallw<<<1, 256, 0, stream>>>(Ws1, Ws2, Wt1, Wt2, wsphe, wtors);

  int nblk = (NT + 63) / 64;
  k_gemm128<<<nblk, 256, 0, stream>>>(x_t, Wq, bq, qbuf, NT);
  k_gemm128<<<nblk, 256, 0, stream>>>(x_s, Wk, bk, kbuf, NS);
  k_gemm128<<<nblk, 256, 0, stream>>>(x_s, Wv, bv, vbuf, NS);

  k_edge_attn<<<EDG / 64, 256, 0, stream>>>(edge_attr, ei, sphe, tors, dist,
                                            qbuf, kbuf, vbuf,
                                            Wdk, bdk, Wdv, bdv, Wo_att, bo_att,
                                            Ws_msg, bs_msg, wsphe, wtors,
                                            smsg, dsum);

  k_edge_f<<<EDG / 64, 256, 0, stream>>>(edge_attr, sphe, tors, Wf, bf,
                                         Wcat_f, bcat_f, wsphe, wtors, out_fji);

  k_dmsg<<<nblk, 256, 0, stream>>>(dsum, Wcat_msg, dmsg);

  k_final<<<nblk, 256, 0, stream>>>(smsg, x_t, dmsg, Wo_msg, bo_msg,
                                    Wfinal, bfinal, out_ht);
}

// Round 2
// 3104.677 us; speedup vs baseline: 2.7504x; 2.7504x over previous
//
#include <hip/hip_runtime.h>
#include <math.h>

static constexpr int H    = 128;
static constexpr int MID  = 64;
static constexpr int NS   = 20000;
static constexpr int NT   = 20000;
static constexpr int EDG  = 320000;
static constexpr int SPH  = 12;  // 3*2^2
static constexpr int TOR  = 6;   // 3*2
static constexpr int TS   = 132; // LDS row stride (floats)

__device__ __forceinline__ float sil(float x) {
  return x / (1.0f + __expf(-x));
}

// acc[32] += sum_i xr[i] * W[i*ldw + j]   (W pre-offset by column base; uniform -> s_load)
template<int K>
__device__ __forceinline__ void kloop32(const float* __restrict__ W, int ldw,
                                        const float* xr, float* acc) {
  #pragma unroll 2
  for (int i0 = 0; i0 < K; i0 += 4) {
    float4 a4 = *(const float4*)(xr + i0);
    const float* w = W + i0 * ldw;
    #pragma unroll
    for (int j = 0; j < 32; ++j) acc[j] = fmaf(a4.x, w[j], acc[j]);
    w += ldw;
    #pragma unroll
    for (int j = 0; j < 32; ++j) acc[j] = fmaf(a4.y, w[j], acc[j]);
    w += ldw;
    #pragma unroll
    for (int j = 0; j < 32; ++j) acc[j] = fmaf(a4.z, w[j], acc[j]);
    w += ldw;
    #pragma unroll
    for (int j = 0; j < 32; ++j) acc[j] = fmaf(a4.w, w[j], acc[j]);
  }
}

// dual version: two weight bases, shared activation
template<int K>
__device__ __forceinline__ void kloop32x2(const float* __restrict__ Wa,
                                          const float* __restrict__ Wb, int ldw,
                                          const float* xr, float* acca, float* accb) {
  #pragma unroll 2
  for (int i0 = 0; i0 < K; i0 += 4) {
    float4 a4 = *(const float4*)(xr + i0);
    float av[4] = {a4.x, a4.y, a4.z, a4.w};
    #pragma unroll
    for (int u = 0; u < 4; ++u) {
      const float* wa = Wa + (i0 + u) * ldw;
      const float* wb = Wb + (i0 + u) * ldw;
      #pragma unroll
      for (int j = 0; j < 32; ++j) acca[j] = fmaf(av[u], wa[j], acca[j]);
      #pragma unroll
      for (int j = 0; j < 32; ++j) accb[j] = fmaf(av[u], wb[j], accb[j]);
    }
  }
}

// segmented flush: X[64][*] (stride TS), rows sorted by target Tbuf[64].
// thread covers col c = tid&127, rows r0..r0+31 (r0 = (tid>>7)*32).
// one atomic per (segment,col) instead of one per (row,col).
__device__ __forceinline__ void flush_seg(const float* __restrict__ X,
                                          const int* __restrict__ Tbuf,
                                          float* __restrict__ out, int ldo, int colbase) {
  int c  = threadIdx.x & 127;
  int r0 = (threadIdx.x >> 7) * 32;
  float acc = X[r0 * TS + c];
  int tcur = Tbuf[r0];
  #pragma unroll 4
  for (int r = r0 + 1; r < r0 + 32; ++r) {
    float v = X[r * TS + c];
    int tn = Tbuf[r];
    if (tn != tcur) {   // wave-uniform branch (r uniform across lanes)
      atomicAdd(&out[(size_t)tcur * ldo + colbase + c], acc);
      acc = v; tcur = tn;
    } else {
      acc += v;
    }
  }
  atomicAdd(&out[(size_t)tcur * ldo + colbase + c], acc);
}

// ---------------- counting sort of edges by target ----------------
__global__ void k_hist(const int* __restrict__ ei, int* __restrict__ deg) {
  int e = blockIdx.x * 256 + threadIdx.x;
  if (e < EDG) atomicAdd(&deg[ei[EDG + e]], 1);
}

__global__ void k_scan(const int* __restrict__ deg, int* __restrict__ cursor) {
  __shared__ int part[256];
  int tid = threadIdx.x;
  const int PER = (NT + 255) / 256;
  int base = tid * PER;
  int sum = 0;
  for (int i = 0; i < PER; ++i) {
    int idx = base + i;
    if (idx < NT) sum += deg[idx];
  }
  part[tid] = sum;
  __syncthreads();
  if (tid == 0) {
    int acc = 0;
    for (int i = 0; i < 256; ++i) { int v = part[i]; part[i] = acc; acc += v; }
  }
  __syncthreads();
  int acc = part[tid];
  for (int i = 0; i < PER; ++i) {
    int idx = base + i;
    if (idx < NT) { cursor[idx] = acc; acc += deg[idx]; }
  }
}

__global__ void k_scatter(const int* __restrict__ ei, int* __restrict__ cursor,
                          int* __restrict__ perm) {
  int e = blockIdx.x * 256 + threadIdx.x;
  if (e < EDG) {
    int t = ei[EDG + e];
    int pos = atomicAdd(&cursor[t], 1);
    perm[pos] = e;
  }
}

// ---------------- tiny: Wsphe = Ws1@Ws2 (12x128), Wtors = Wt1@Wt2 (6x128) ----------------
__global__ void k_smallw(const float* __restrict__ Ws1, const float* __restrict__ Ws2,
                         const float* __restrict__ Wt1, const float* __restrict__ Wt2,
                         float* __restrict__ Wsphe, float* __restrict__ Wtors) {
  int tid = threadIdx.x;
  for (int o = tid; o < SPH * H; o += 256) {
    int i = o >> 7, c = o & 127;
    float acc = 0.f;
    for (int m = 0; m < MID; ++m) acc = fmaf(Ws1[i * MID + m], Ws2[m * H + c], acc);
    Wsphe[o] = acc;
  }
  for (int o = tid; o < TOR * H; o += 256) {
    int i = o >> 7, c = o & 127;
    float acc = 0.f;
    for (int m = 0; m < MID; ++m) acc = fmaf(Wt1[i * MID + m], Wt2[m * H + c], acc);
    Wtors[o] = acc;
  }
}

// ---------------- node GEMM: Out(M x128) = A(M x128) @ W(128x128) + b ----------------
__global__ __launch_bounds__(256, 4)
void k_gemm128(const float* __restrict__ A, const float* __restrict__ W,
               const float* __restrict__ bias, float* __restrict__ Out, int M) {
  __shared__ float X[64 * TS];
  int tid = threadIdx.x;
  int r0 = blockIdx.x * 64;
  for (int idx = tid; idx < 64 * 32; idx += 256) {
    int r = idx >> 5, seg = idx & 31;
    int row = r0 + r;
    float4 val = make_float4(0.f, 0.f, 0.f, 0.f);
    if (row < M) val = *(const float4*)(A + row * H + seg * 4);
    *(float4*)(X + r * TS + seg * 4) = val;
  }
  __syncthreads();
  int lane = tid & 63, wave = tid >> 6;
  int c0 = __builtin_amdgcn_readfirstlane(wave * 32);
  float acc[32];
  #pragma unroll
  for (int j = 0; j < 32; ++j) acc[j] = bias[c0 + j];
  kloop32<128>(W + c0, H, X + lane * TS, acc);
  int row = r0 + lane;
  if (row < M) {
    #pragma unroll
    for (int j4 = 0; j4 < 8; ++j4) {
      float4 o4 = make_float4(acc[j4*4], acc[j4*4+1], acc[j4*4+2], acc[j4*4+3]);
      *(float4*)(Out + row * H + c0 + j4 * 4) = o4;
    }
  }
}

// ---------------- edge kernel A (sorted): dk/dv -> attn -> v_j -> s -> segmented flush ----------------
__global__ __launch_bounds__(256, 4)
void k_edge_attn(const float* __restrict__ edge_attr, const int* __restrict__ ei,
                 const int* __restrict__ perm,
                 const float* __restrict__ sphe, const float* __restrict__ tors,
                 const float* __restrict__ dist,
                 const float* __restrict__ q, const float* __restrict__ kk,
                 const float* __restrict__ vv,
                 const float* __restrict__ Wdk, const float* __restrict__ bdk,
                 const float* __restrict__ Wdv, const float* __restrict__ bdv,
                 const float* __restrict__ Wo_att, const float* __restrict__ bo_att,
                 const float* __restrict__ Ws_msg, const float* __restrict__ bs_msg,
                 const float* __restrict__ Wsphe, const float* __restrict__ Wtors,
                 float* __restrict__ s_msg, float* __restrict__ dsum) {
  __shared__ float X[64 * TS];
  __shared__ int Ebuf[64];
  __shared__ int Tbuf[64];
  int tid = threadIdx.x;
  int b0 = blockIdx.x * 64;
  if (tid < 64) {
    int ee = perm[b0 + tid];
    Ebuf[tid] = ee;
    Tbuf[tid] = ei[EDG + ee];
  }
  __syncthreads();
  for (int idx = tid; idx < 64 * 32; idx += 256) {
    int r = idx >> 5, seg = idx & 31;
    *(float4*)(X + r * TS + seg * 4) =
        *(const float4*)(edge_attr + (size_t)Ebuf[r] * H + seg * 4);
  }
  __syncthreads();
  int lane = tid & 63, wave = tid >> 6;
  int c0 = __builtin_amdgcn_readfirstlane(wave * 32);
  int e = Ebuf[lane];
  int t = Tbuf[lane];
  int s = ei[e];
  const float* xr = X + lane * TS;

  // phase 1: dk, dv = silu(ea @ W + b)
  float dk[32], dv[32];
  #pragma unroll
  for (int j = 0; j < 32; ++j) { dk[j] = bdk[c0 + j]; dv[j] = bdv[c0 + j]; }
  kloop32x2<128>(Wdk + c0, Wdv + c0, H, xr, dk, dv);
  #pragma unroll
  for (int j = 0; j < 32; ++j) { dk[j] = sil(dk[j]); dv[j] = sil(dv[j]); }

  // attn for this wave's two heads
  float ah0 = 0.f, ah1 = 0.f;
  #pragma unroll
  for (int j8 = 0; j8 < 8; ++j8) {
    float4 q4 = *(const float4*)(q  + (size_t)t * H + c0 + j8 * 4);
    float4 k4 = *(const float4*)(kk + (size_t)s * H + c0 + j8 * 4);
    float p = q4.x * k4.x * dk[j8*4]   + q4.y * k4.y * dk[j8*4+1]
            + q4.z * k4.z * dk[j8*4+2] + q4.w * k4.w * dk[j8*4+3];
    if (j8 < 4) ah0 += p; else ah1 += p;
  }
  float dd = dist[e];
  float cutv = (dd < 5.0f) ? 0.5f * (__cosf(0.6283185307179586f * dd) + 1.0f) : 0.0f;
  float a0 = sil(ah0) * cutv;
  float a1 = sil(ah1) * cutv;

  // vjpre = v[src] * dv * attn
  float vj[32];
  #pragma unroll
  for (int j8 = 0; j8 < 8; ++j8) {
    float4 v4 = *(const float4*)(vv + (size_t)s * H + c0 + j8 * 4);
    float aa = (j8 < 4) ? a0 : a1;
    vj[j8*4]   = v4.x * dv[j8*4]   * aa;
    vj[j8*4+1] = v4.y * dv[j8*4+1] * aa;
    vj[j8*4+2] = v4.z * dv[j8*4+2] * aa;
    vj[j8*4+3] = v4.w * dv[j8*4+3] * aa;
  }
  __syncthreads();          // everyone done reading ea
  #pragma unroll
  for (int j4 = 0; j4 < 8; ++j4) {
    float4 o4 = make_float4(vj[j4*4], vj[j4*4+1], vj[j4*4+2], vj[j4*4+3]);
    *(float4*)(X + lane * TS + c0 + j4 * 4) = o4;
  }
  __syncthreads();

  // phase 2: v_j = silu(vjpre @ Wo_att + b)
  float acc[32];
  #pragma unroll
  for (int j = 0; j < 32; ++j) acc[j] = bo_att[c0 + j];
  kloop32<128>(Wo_att + c0, H, xr, acc);
  #pragma unroll
  for (int j = 0; j < 32; ++j) vj[j] = sil(acc[j]);
  __syncthreads();          // everyone done reading vjpre
  #pragma unroll
  for (int j4 = 0; j4 < 8; ++j4) {
    float4 o4 = make_float4(vj[j4*4], vj[j4*4+1], vj[j4*4+2], vj[j4*4+3]);
    *(float4*)(X + lane * TS + c0 + j4 * 4) = o4;
  }
  __syncthreads();

  // flush v_j -> s_msg (reads X; no X writes)
  flush_seg(X, Tbuf, s_msg, H, 0);

  // phase 3: s = silu(v_j @ Ws_msg + b), cols c1..c1+63 (reads X too)
  int c1 = __builtin_amdgcn_readfirstlane(wave * 64);
  float s0[32], s1[32];
  #pragma unroll
  for (int j = 0; j < 32; ++j) { s0[j] = bs_msg[c1 + j]; s1[j] = bs_msg[c1 + 32 + j]; }
  kloop32x2<128>(Ws_msg + c1, Ws_msg + c1 + 32, 2 * H, xr, s0, s1);
  #pragma unroll
  for (int j = 0; j < 32; ++j) { s0[j] = sil(s0[j]); s1[j] = sil(s1[j]); }

  // multiply by d1/d2 (recomputed from collapsed weights)
  if (wave < 2) {
    const float4* spp = (const float4*)(sphe + (size_t)e * SPH);
    float4 sa = spp[0], sb = spp[1], sc = spp[2];
    float sp[12] = {sa.x, sa.y, sa.z, sa.w, sb.x, sb.y, sb.z, sb.w, sc.x, sc.y, sc.z, sc.w};
    #pragma unroll
    for (int j = 0; j < 32; ++j) {
      float d = 0.f;
      #pragma unroll
      for (int i = 0; i < 12; ++i) d = fmaf(sp[i], Wsphe[i * H + c1 + j], d);
      s0[j] *= d;
    }
    #pragma unroll
    for (int j = 0; j < 32; ++j) {
      float d = 0.f;
      #pragma unroll
      for (int i = 0; i < 12; ++i) d = fmaf(sp[i], Wsphe[i * H + c1 + 32 + j], d);
      s1[j] *= d;
    }
  } else {
    const float* tpp = tors + (size_t)e * TOR;
    float tp[6];
    #pragma unroll
    for (int i = 0; i < 6; ++i) tp[i] = tpp[i];
    int d0 = c1 - 128;
    #pragma unroll
    for (int j = 0; j < 32; ++j) {
      float d = 0.f;
      #pragma unroll
      for (int i = 0; i < 6; ++i) d = fmaf(tp[i], Wtors[i * H + d0 + j], d);
      s0[j] *= d;
    }
    #pragma unroll
    for (int j = 0; j < 32; ++j) {
      float d = 0.f;
      #pragma unroll
      for (int i = 0; i < 6; ++i) d = fmaf(tp[i], Wtors[i * H + d0 + 32 + j], d);
      s1[j] *= d;
    }
  }
  __syncthreads();   // all reads of X (flush + phase3) complete

  // round lo: waves 0,1 stage d_ji cols 0..127
  if (wave < 2) {
    #pragma unroll
    for (int j4 = 0; j4 < 8; ++j4) {
      float4 o4 = make_float4(s0[j4*4], s0[j4*4+1], s0[j4*4+2], s0[j4*4+3]);
      *(float4*)(X + lane * TS + c1 + j4 * 4) = o4;
    }
    #pragma unroll
    for (int j4 = 0; j4 < 8; ++j4) {
      float4 o4 = make_float4(s1[j4*4], s1[j4*4+1], s1[j4*4+2], s1[j4*4+3]);
      *(float4*)(X + lane * TS + c1 + 32 + j4 * 4) = o4;
    }
  }
  __syncthreads();
  flush_seg(X, Tbuf, dsum, 2 * H, 0);
  __syncthreads();

  // round hi: waves 2,3 stage d_ji cols 128..255
  if (wave >= 2) {
    int cb = c1 - 128;
    #pragma unroll
    for (int j4 = 0; j4 < 8; ++j4) {
      float4 o4 = make_float4(s0[j4*4], s0[j4*4+1], s0[j4*4+2], s0[j4*4+3]);
      *(float4*)(X + lane * TS + cb + j4 * 4) = o4;
    }
    #pragma unroll
    for (int j4 = 0; j4 < 8; ++j4) {
      float4 o4 = make_float4(s1[j4*4], s1[j4*4+1], s1[j4*4+2], s1[j4*4+3]);
      *(float4*)(X + lane * TS + cb + 32 + j4 * 4) = o4;
    }
  }
  __syncthreads();
  flush_seg(X, Tbuf, dsum, 2 * H, 128);
}

// ---------------- edge kernel B: f path -> f_ji (unchanged control) ----------------
__global__ __launch_bounds__(256, 2)
void k_edge_f(const float* __restrict__ edge_attr,
              const float* __restrict__ sphe, const float* __restrict__ tors,
              const float* __restrict__ Wf, const float* __restrict__ bf,
              const float* __restrict__ Wcat_f, const float* __restrict__ bcat_f,
              const float* __restrict__ Wsphe, const float* __restrict__ Wtors,
              float* __restrict__ out_fji) {
  __shared__ float X[64 * TS];
  __shared__ float Y[64 * TS];
  int tid = threadIdx.x;
  int e0 = blockIdx.x * 64;
  for (int idx = tid; idx < 64 * 32; idx += 256) {
    int r = idx >> 5, seg = idx & 31;
    *(float4*)(X + r * TS + seg * 4) = *(const float4*)(edge_attr + (size_t)(e0 + r) * H + seg * 4);
  }
  __syncthreads();
  int lane = tid & 63, wave = tid >> 6;
  int c0 = __builtin_amdgcn_readfirstlane(wave * 32);
  int e = e0 + lane;
  const float* xr = X + lane * TS;
  const float* yr = Y + lane * TS;

  const float4* spp = (const float4*)(sphe + (size_t)e * SPH);
  float4 sa = spp[0], sb = spp[1], sc = spp[2];
  float sp[12] = {sa.x, sa.y, sa.z, sa.w, sb.x, sb.y, sb.z, sb.w, sc.x, sc.y, sc.z, sc.w};
  const float* tpp = tors + (size_t)e * TOR;
  float tp[6];
  #pragma unroll
  for (int i = 0; i < 6; ++i) tp[i] = tpp[i];

  // phase 1: f2 = silu(ea @ Wf[:,128:256] + b), y = f2 * d1
  float acc[32];
  #pragma unroll
  for (int j = 0; j < 32; ++j) acc[j] = bf[H + c0 + j];
  kloop32<128>(Wf + H + c0, 3 * H, xr, acc);
  #pragma unroll
  for (int j = 0; j < 32; ++j) {
    float d = 0.f;
    #pragma unroll
    for (int i = 0; i < 12; ++i) d = fmaf(sp[i], Wsphe[i * H + c0 + j], d);
    acc[j] = sil(acc[j]) * d;
  }
  #pragma unroll
  for (int j4 = 0; j4 < 8; ++j4) {
    float4 o4 = make_float4(acc[j4*4], acc[j4*4+1], acc[j4*4+2], acc[j4*4+3]);
    *(float4*)(Y + lane * TS + c0 + j4 * 4) = o4;
  }
  __syncthreads();

  // phase 2: acco = y @ Wcat_f[0:128]
  float acco[32];
  #pragma unroll
  for (int j = 0; j < 32; ++j) acco[j] = 0.f;
  kloop32<128>(Wcat_f + c0, H, yr, acco);
  __syncthreads();

  // phase 3: f3 = silu(ea @ Wf[:,256:384] + b), y = f3 * d2
  #pragma unroll
  for (int j = 0; j < 32; ++j) acc[j] = bf[2 * H + c0 + j];
  kloop32<128>(Wf + 2 * H + c0, 3 * H, xr, acc);
  #pragma unroll
  for (int j = 0; j < 32; ++j) {
    float d = 0.f;
    #pragma unroll
    for (int i = 0; i < 6; ++i) d = fmaf(tp[i], Wtors[i * H + c0 + j], d);
    acc[j] = sil(acc[j]) * d;
  }
  #pragma unroll
  for (int j4 = 0; j4 < 8; ++j4) {
    float4 o4 = make_float4(acc[j4*4], acc[j4*4+1], acc[j4*4+2], acc[j4*4+3]);
    *(float4*)(Y + lane * TS + c0 + j4 * 4) = o4;
  }
  __syncthreads();

  // phase 4: acco += y @ Wcat_f[128:256]
  kloop32<128>(Wcat_f + H * H + c0, H, yr, acco);

  // phase 5: f1 = silu(ea @ Wf[:,0:128] + b); out = f1 + silu(acco + bcat)
  #pragma unroll
  for (int j = 0; j < 32; ++j) acc[j] = bf[c0 + j];
  kloop32<128>(Wf + c0, 3 * H, xr, acc);
  #pragma unroll
  for (int j = 0; j < 32; ++j) acc[j] = sil(acc[j]) + sil(acco[j] + bcat_f[c0 + j]);
  #pragma unroll
  for (int j4 = 0; j4 < 8; ++j4) {
    float4 o4 = make_float4(acc[j4*4], acc[j4*4+1], acc[j4*4+2], acc[j4*4+3]);
    *(float4*)(out_fji + (size_t)e * H + c0 + j4 * 4) = o4;
  }
}

// ---------------- d_msg = dsum @ Wcat_msg  (M=NT, K=256, N=128) ----------------
__global__ __launch_bounds__(256, 2)
void k_dmsg(const float* __restrict__ dsum, const float* __restrict__ Wcat_msg,
            float* __restrict__ d_msg) {
  __shared__ float X[64 * 260];
  int tid = threadIdx.x;
  int r0 = blockIdx.x * 64;
  for (int idx = tid; idx < 64 * 64; idx += 256) {
    int r = idx >> 6, seg = idx & 63;
    int row = r0 + r;
    float4 val = make_float4(0.f, 0.f, 0.f, 0.f);
    if (row < NT) val = *(const float4*)(dsum + (size_t)row * 2 * H + seg * 4);
    *(float4*)(X + r * 260 + seg * 4) = val;
  }
  __syncthreads();
  int lane = tid & 63, wave = tid >> 6;
  int c0 = __builtin_amdgcn_readfirstlane(wave * 32);
  float acc[32];
  #pragma unroll
  for (int j = 0; j < 32; ++j) acc[j] = 0.f;
  kloop32<256>(Wcat_msg + c0, H, X + lane * 260, acc);
  int row = r0 + lane;
  if (row < NT) {
    #pragma unroll
    for (int j4 = 0; j4 < 8; ++j4) {
      float4 o4 = make_float4(acc[j4*4], acc[j4*4+1], acc[j4*4+2], acc[j4*4+3]);
      *(float4*)(d_msg + (size_t)row * H + c0 + j4 * 4) = o4;
    }
  }
}

// ---------------- final: o = s_msg@Wo_msg+b; z = o1 + o2*d_msg; h = silu([x_t,z]@Wfinal+b) ----------------
__global__ __launch_bounds__(256, 2)
void k_final(const float* __restrict__ s_msg, const float* __restrict__ x_t,
             const float* __restrict__ d_msg,
             const float* __restrict__ Wo_msg, const float* __restrict__ bo_msg,
             const float* __restrict__ Wfinal, const float* __restrict__ bfinal,
             float* __restrict__ out_ht) {
  __shared__ float SM[64 * TS];
  __shared__ float XT[64 * TS];
  int tid = threadIdx.x;
  int r0 = blockIdx.x * 64;
  for (int idx = tid; idx < 64 * 32; idx += 256) {
    int r = idx >> 5, seg = idx & 31;
    int row = r0 + r;
    float4 v1 = make_float4(0.f, 0.f, 0.f, 0.f), v2 = v1;
    if (row < NT) {
      v1 = *(const float4*)(s_msg + (size_t)row * H + seg * 4);
      v2 = *(const float4*)(x_t   + (size_t)row * H + seg * 4);
    }
    *(float4*)(SM + r * TS + seg * 4) = v1;
    *(float4*)(XT + r * TS + seg * 4) = v2;
  }
  __syncthreads();
  int lane = tid & 63, wave = tid >> 6;
  int c0 = __builtin_amdgcn_readfirstlane(wave * 32);
  int row = r0 + lane;
  float acc1[32], acc2[32];
  #pragma unroll
  for (int j = 0; j < 32; ++j) { acc1[j] = bo_msg[c0 + j]; acc2[j] = bo_msg[H + c0 + j]; }
  kloop32x2<128>(Wo_msg + c0, Wo_msg + H + c0, 2 * H, SM + lane * TS, acc1, acc2);
  // z = o1 + o2 * d_msg
  float z[32];
  if (row < NT) {
    #pragma unroll
    for (int j4 = 0; j4 < 8; ++j4) {
      float4 dm = *(const float4*)(d_msg + (size_t)row * H + c0 + j4 * 4);
      z[j4*4]   = acc1[j4*4]   + acc2[j4*4]   * dm.x;
      z[j4*4+1] = acc1[j4*4+1] + acc2[j4*4+1] * dm.y;
      z[j4*4+2] = acc1[j4*4+2] + acc2[j4*4+2] * dm.z;
      z[j4*4+3] = acc1[j4*4+3] + acc2[j4*4+3] * dm.w;
    }
  } else {
    #pragma unroll
    for (int j = 0; j < 32; ++j) z[j] = 0.f;
  }
  __syncthreads();
  #pragma unroll
  for (int j4 = 0; j4 < 8; ++j4) {
    float4 o4 = make_float4(z[j4*4], z[j4*4+1], z[j4*4+2], z[j4*4+3]);
    *(float4*)(SM + lane * TS + c0 + j4 * 4) = o4;
  }
  __syncthreads();
  float acc[32];
  #pragma unroll
  for (int j = 0; j < 32; ++j) acc[j] = bfinal[c0 + j];
  kloop32<128>(Wfinal + c0, H, XT + lane * TS, acc);             // x_t part (rows 0..127)
  kloop32<128>(Wfinal + H * H + c0, H, SM + lane * TS, acc);     // z part (rows 128..255)
  if (row < NT) {
    #pragma unroll
    for (int j4 = 0; j4 < 8; ++j4) {
      float4 o4 = make_float4(sil(acc[j4*4]), sil(acc[j4*4+1]), sil(acc[j4*4+2]), sil(acc[j4*4+3]));
      *(float4*)(out_ht + (size_t)row * H + c0 + j4 * 4) = o4;
    }
  }
}

extern "C" void kernel_launch(void* const* d_in, const int* in_sizes, int n_in,
                              void* d_out, int out_size, void* d_ws, size_t ws_size,
                              hipStream_t stream) {
  const float* x_s       = (const float*)d_in[0];
  const float* x_t       = (const float*)d_in[1];
  const int*   ei        = (const int*)  d_in[2];
  const float* edge_attr = (const float*)d_in[3];
  const float* sphe      = (const float*)d_in[4];
  const float* tors      = (const float*)d_in[5];
  const float* dist      = (const float*)d_in[6];
  const float* Ws1       = (const float*)d_in[7];
  const float* Ws2       = (const float*)d_in[8];
  const float* Wt1       = (const float*)d_in[9];
  const float* Wt2       = (const float*)d_in[10];
  const float* Wq        = (const float*)d_in[11];
  const float* bq        = (const float*)d_in[12];
  const float* Wk        = (const float*)d_in[13];
  const float* bk        = (const float*)d_in[14];
  const float* Wv        = (const float*)d_in[15];
  const float* bv        = (const float*)d_in[16];
  const float* Wdk       = (const float*)d_in[17];
  const float* bdk       = (const float*)d_in[18];
  const float* Wdv       = (const float*)d_in[19];
  const float* bdv       = (const float*)d_in[20];
  const float* Wo_att    = (const float*)d_in[21];
  const float* bo_att    = (const float*)d_in[22];
  const float* Ws_msg    = (const float*)d_in[23];
  const float* bs_msg    = (const float*)d_in[24];
  const float* Wcat_msg  = (const float*)d_in[25];
  const float* Wo_msg    = (const float*)d_in[26];
  const float* bo_msg    = (const float*)d_in[27];
  const float* Wfinal    = (const float*)d_in[28];
  const float* bfinal    = (const float*)d_in[29];
  const float* Wf        = (const float*)d_in[30];
  const float* bf        = (const float*)d_in[31];
  const float* Wcat_f    = (const float*)d_in[32];
  const float* bcat_f    = (const float*)d_in[33];

  float* ws = (float*)d_ws;
  float* qbuf  = ws;                         // NT*H
  float* kbuf  = qbuf  + (size_t)NT * H;     // NS*H
  float* vbuf  = kbuf  + (size_t)NS * H;     // NS*H
  float* smsg  = vbuf  + (size_t)NS * H;     // NT*H
  float* dsum  = smsg  + (size_t)NT * H;     // NT*2H
  float* dmsg  = dsum  + (size_t)NT * 2 * H; // NT*H
  float* wsphe = dmsg  + (size_t)NT * H;     // 12*128
  float* wtors = wsphe + SPH * H;            // 6*128
  int*   deg    = (int*)(wtors + TOR * H);   // NT
  int*   cursor = deg + NT;                  // NT
  int*   perm   = cursor + NT;               // EDG

  float* out_ht  = (float*)d_out;
  float* out_fji = out_ht + (size_t)NT * H;

  hipMemsetAsync(smsg, 0, (size_t)NT * H * sizeof(float), stream);
  hipMemsetAsync(dsum, 0, (size_t)NT * 2 * H * sizeof(float), stream);
  hipMemsetAsync(deg, 0, (size_t)NT * sizeof(int), stream);

  // counting sort of edges by target
  k_hist<<<(EDG + 255) / 256, 256, 0, stream>>>(ei, deg);
  k_scan<<<1, 256, 0, stream>>>(deg, cursor);
  k_scatter<<<(EDG + 255) / 256, 256, 0, stream>>>(ei, cursor, perm);

  k_smallw<<<1, 256, 0, stream>>>(Ws1, Ws2, Wt1, Wt2, wsphe, wtors);

  int nblk = (NT + 63) / 64;
  k_gemm128<<<nblk, 256, 0, stream>>>(x_t, Wq, bq, qbuf, NT);
  k_gemm128<<<nblk, 256, 0, stream>>>(x_s, Wk, bk, kbuf, NS);
  k_gemm128<<<nblk, 256, 0, stream>>>(x_s, Wv, bv, vbuf, NS);

  k_edge_attn<<<EDG / 64, 256, 0, stream>>>(edge_attr, ei, perm, sphe, tors, dist,
                                            qbuf, kbuf, vbuf,
                                            Wdk, bdk, Wdv, bdv, Wo_att, bo_att,
                                            Ws_msg, bs_msg, wsphe, wtors,
                                            smsg, dsum);

  k_edge_f<<<EDG / 64, 256, 0, stream>>>(edge_attr, sphe, tors, Wf, bf,
                                         Wcat_f, bcat_f, wsphe, wtors, out_fji);

  k_dmsg<<<nblk, 256, 0, stream>>>(dsum, Wcat_msg, dmsg);

  k_final<<<nblk, 256, 0, stream>>>(smsg, x_t, dmsg, Wo_msg, bo_msg,
                                    Wfinal, bfinal, out_ht);
}

// Round 7
// 2103.339 us; speedup vs baseline: 4.0598x; 1.4761x over previous
//
#include <hip/hip_runtime.h>
#include <math.h>

static constexpr int H    = 128;
static constexpr int MID  = 64;
static constexpr int NS   = 20000;
static constexpr int NT   = 20000;
static constexpr int EDG  = 320000;
static constexpr int SPH  = 12;  // 3*2^2
static constexpr int TOR  = 6;   // 3*2
static constexpr int TS   = 132; // LDS row stride (floats)

typedef unsigned long long u64;
typedef unsigned int u32;
typedef unsigned short ushort_t;

using bf8   = __attribute__((ext_vector_type(8))) short;
using f32x4 = __attribute__((ext_vector_type(4))) float;

__device__ __forceinline__ float sil(float x) {
  return x / (1.0f + __expf(-x));
}

__device__ __forceinline__ ushort_t f2bf(float x) {
  u32 u = __float_as_uint(x);
  u32 r = u + 0x7FFFu + ((u >> 16) & 1u);
  return (ushort_t)(r >> 16);
}
__device__ __forceinline__ float bf2f(ushort_t h) {
  return __uint_as_float(((u32)h) << 16);
}

__device__ __forceinline__ bf8 ld_lds_frag(const char* base, u32 b0, u32 b1) {
  union { u64 u[2]; bf8 v; } X;
  X.u[0] = *(const u64*)(base + b0);
  X.u[1] = *(const u64*)(base + b1);
  return X.v;
}
__device__ __forceinline__ bf8 ld_g_frag(const ushort_t* p) {
  union { u64 u[2]; bf8 v; } X;
  X.u[0] = *(const u64*)(p);
  X.u[1] = *(const u64*)(p + 16);
  return X.v;
}

// acc[32] += sum_i xr[i] * W[i*ldw + j]
template<int K>
__device__ __forceinline__ void kloop32(const float* __restrict__ W, int ldw,
                                        const float* xr, float* acc) {
  #pragma unroll 2
  for (int i0 = 0; i0 < K; i0 += 4) {
    float4 a4 = *(const float4*)(xr + i0);
    const float* w = W + i0 * ldw;
    #pragma unroll
    for (int j = 0; j < 32; ++j) acc[j] = fmaf(a4.x, w[j], acc[j]);
    w += ldw;
    #pragma unroll
    for (int j = 0; j < 32; ++j) acc[j] = fmaf(a4.y, w[j], acc[j]);
    w += ldw;
    #pragma unroll
    for (int j = 0; j < 32; ++j) acc[j] = fmaf(a4.z, w[j], acc[j]);
    w += ldw;
    #pragma unroll
    for (int j = 0; j < 32; ++j) acc[j] = fmaf(a4.w, w[j], acc[j]);
  }
}

template<int K>
__device__ __forceinline__ void kloop32x2(const float* __restrict__ Wa,
                                          const float* __restrict__ Wb, int ldw,
                                          const float* xr, float* acca, float* accb) {
  #pragma unroll 2
  for (int i0 = 0; i0 < K; i0 += 4) {
    float4 a4 = *(const float4*)(xr + i0);
    float av[4] = {a4.x, a4.y, a4.z, a4.w};
    #pragma unroll
    for (int u = 0; u < 4; ++u) {
      const float* wa = Wa + (i0 + u) * ldw;
      const float* wb = Wb + (i0 + u) * ldw;
      #pragma unroll
      for (int j = 0; j < 32; ++j) acca[j] = fmaf(av[u], wa[j], acca[j]);
      #pragma unroll
      for (int j = 0; j < 32; ++j) accb[j] = fmaf(av[u], wb[j], accb[j]);
    }
  }
}

// segmented flush over sorted targets
__device__ __forceinline__ void flush_seg(const float* __restrict__ X,
                                          const int* __restrict__ Tbuf,
                                          float* __restrict__ out, int ldo, int colbase) {
  int c  = threadIdx.x & 127;
  int r0 = (threadIdx.x >> 7) * 32;
  float acc = X[r0 * TS + c];
  int tcur = Tbuf[r0];
  #pragma unroll 4
  for (int r = r0 + 1; r < r0 + 32; ++r) {
    float v = X[r * TS + c];
    int tn = Tbuf[r];
    if (tn != tcur) {
      atomicAdd(&out[(size_t)tcur * ldo + colbase + c], acc);
      acc = v; tcur = tn;
    } else {
      acc += v;
    }
  }
  atomicAdd(&out[(size_t)tcur * ldo + colbase + c], acc);
}

// ---------------- counting sort ----------------
__global__ void k_hist(const int* __restrict__ ei, int* __restrict__ deg) {
  int e = blockIdx.x * 256 + threadIdx.x;
  if (e < EDG) atomicAdd(&deg[ei[EDG + e]], 1);
}

__global__ void k_scan(const int* __restrict__ deg, int* __restrict__ cursor) {
  __shared__ int part[256];
  int tid = threadIdx.x;
  const int PER = (NT + 255) / 256;
  int base = tid * PER;
  int sum = 0;
  for (int i = 0; i < PER; ++i) {
    int idx = base + i;
    if (idx < NT) sum += deg[idx];
  }
  part[tid] = sum;
  __syncthreads();
  if (tid == 0) {
    int acc = 0;
    for (int i = 0; i < 256; ++i) { int v = part[i]; part[i] = acc; acc += v; }
  }
  __syncthreads();
  int acc = part[tid];
  for (int i = 0; i < PER; ++i) {
    int idx = base + i;
    if (idx < NT) { cursor[idx] = acc; acc += deg[idx]; }
  }
}

__global__ void k_scatter(const int* __restrict__ ei, int* __restrict__ cursor,
                          int* __restrict__ perm) {
  int e = blockIdx.x * 256 + threadIdx.x;
  if (e < EDG) {
    int t = ei[EDG + e];
    int pos = atomicAdd(&cursor[t], 1);
    perm[pos] = e;
  }
}

// ---------------- Wsphe = Ws1@Ws2 (fp32, for attn kernel) ----------------
__global__ void k_smallw(const float* __restrict__ Ws1, const float* __restrict__ Ws2,
                         const float* __restrict__ Wt1, const float* __restrict__ Wt2,
                         float* __restrict__ Wsphe, float* __restrict__ Wtors) {
  int tid = threadIdx.x;
  for (int o = tid; o < SPH * H; o += 256) {
    int i = o >> 7, c = o & 127;
    float acc = 0.f;
    for (int m = 0; m < MID; ++m) acc = fmaf(Ws1[i * MID + m], Ws2[m * H + c], acc);
    Wsphe[o] = acc;
  }
  for (int o = tid; o < TOR * H; o += 256) {
    int i = o >> 7, c = o & 127;
    float acc = 0.f;
    for (int m = 0; m < MID; ++m) acc = fmaf(Wt1[i * MID + m], Wt2[m * H + c], acc);
    Wtors[o] = acc;
  }
}

// ---------------- weight prep: transposed bf16 (hi/lo for Wf) ----------------
__global__ void k_prepw(const float* __restrict__ Wf, const float* __restrict__ Wcat_f,
                        const float* __restrict__ Ws1, const float* __restrict__ Ws2,
                        const float* __restrict__ Wt1, const float* __restrict__ Wt2,
                        ushort_t* __restrict__ wfT_hi, ushort_t* __restrict__ wfT_lo,
                        ushort_t* __restrict__ wcatT,
                        ushort_t* __restrict__ wspheT, ushort_t* __restrict__ wtorsT) {
  int idx = blockIdx.x * 256 + threadIdx.x;
  if (idx < 384 * 128) {                 // wfT[n][k] = Wf[k][n], hi/lo
    int n = idx >> 7, k = idx & 127;
    float v = Wf[k * 384 + n];
    ushort_t h = f2bf(v);
    wfT_hi[idx] = h;
    wfT_lo[idx] = f2bf(v - bf2f(h));
  }
  if (idx < 128 * 256) {                 // wcatT[n][k] = Wcat_f[k][n]
    int n = idx >> 8, k = idx & 255;
    wcatT[idx] = f2bf(Wcat_f[k * 128 + n]);
  }
  if (idx < 128 * 32) {                  // wspheT[n][k] = (Ws1@Ws2)[k][n], k<12
    int n = idx >> 5, k = idx & 31;
    float v = 0.f;
    if (k < SPH) {
      for (int m = 0; m < MID; ++m) v = fmaf(Ws1[k * MID + m], Ws2[m * H + n], v);
    }
    wspheT[idx] = f2bf(v);
    float v2 = 0.f;
    if (k < TOR) {
      for (int m = 0; m < MID; ++m) v2 = fmaf(Wt1[k * MID + m], Wt2[m * H + n], v2);
    }
    wtorsT[idx] = f2bf(v2);
  }
}

// ---------------- node GEMM ----------------
__global__ __launch_bounds__(256, 4)
void k_gemm128(const float* __restrict__ A, const float* __restrict__ W,
               const float* __restrict__ bias, float* __restrict__ Out, int M) {
  __shared__ float X[64 * TS];
  int tid = threadIdx.x;
  int r0 = blockIdx.x * 64;
  for (int idx = tid; idx < 64 * 32; idx += 256) {
    int r = idx >> 5, seg = idx & 31;
    int row = r0 + r;
    float4 val = make_float4(0.f, 0.f, 0.f, 0.f);
    if (row < M) val = *(const float4*)(A + row * H + seg * 4);
    *(float4*)(X + r * TS + seg * 4) = val;
  }
  __syncthreads();
  int lane = tid & 63, wave = tid >> 6;
  int c0 = __builtin_amdgcn_readfirstlane(wave * 32);
  float acc[32];
  #pragma unroll
  for (int j = 0; j < 32; ++j) acc[j] = bias[c0 + j];
  kloop32<128>(W + c0, H, X + lane * TS, acc);
  int row = r0 + lane;
  if (row < M) {
    #pragma unroll
    for (int j4 = 0; j4 < 8; ++j4) {
      float4 o4 = make_float4(acc[j4*4], acc[j4*4+1], acc[j4*4+2], acc[j4*4+3]);
      *(float4*)(Out + row * H + c0 + j4 * 4) = o4;
    }
  }
}

// ---------------- edge kernel A (sorted + segmented flush) ----------------
__global__ __launch_bounds__(256, 4)
void k_edge_attn(const float* __restrict__ edge_attr, const int* __restrict__ ei,
                 const int* __restrict__ perm,
                 const float* __restrict__ sphe, const float* __restrict__ tors,
                 const float* __restrict__ dist,
                 const float* __restrict__ q, const float* __restrict__ kk,
                 const float* __restrict__ vv,
                 const float* __restrict__ Wdk, const float* __restrict__ bdk,
                 const float* __restrict__ Wdv, const float* __restrict__ bdv,
                 const float* __restrict__ Wo_att, const float* __restrict__ bo_att,
                 const float* __restrict__ Ws_msg, const float* __restrict__ bs_msg,
                 const float* __restrict__ Wsphe, const float* __restrict__ Wtors,
                 float* __restrict__ s_msg, float* __restrict__ dsum) {
  __shared__ float X[64 * TS];
  __shared__ int Ebuf[64];
  __shared__ int Tbuf[64];
  int tid = threadIdx.x;
  int b0 = blockIdx.x * 64;
  if (tid < 64) {
    int ee = perm[b0 + tid];
    Ebuf[tid] = ee;
    Tbuf[tid] = ei[EDG + ee];
  }
  __syncthreads();
  for (int idx = tid; idx < 64 * 32; idx += 256) {
    int r = idx >> 5, seg = idx & 31;
    *(float4*)(X + r * TS + seg * 4) =
        *(const float4*)(edge_attr + (size_t)Ebuf[r] * H + seg * 4);
  }
  __syncthreads();
  int lane = tid & 63, wave = tid >> 6;
  int c0 = __builtin_amdgcn_readfirstlane(wave * 32);
  int e = Ebuf[lane];
  int t = Tbuf[lane];
  int s = ei[e];
  const float* xr = X + lane * TS;

  float dk[32], dv[32];
  #pragma unroll
  for (int j = 0; j < 32; ++j) { dk[j] = bdk[c0 + j]; dv[j] = bdv[c0 + j]; }
  kloop32x2<128>(Wdk + c0, Wdv + c0, H, xr, dk, dv);
  #pragma unroll
  for (int j = 0; j < 32; ++j) { dk[j] = sil(dk[j]); dv[j] = sil(dv[j]); }

  float ah0 = 0.f, ah1 = 0.f;
  #pragma unroll
  for (int j8 = 0; j8 < 8; ++j8) {
    float4 q4 = *(const float4*)(q  + (size_t)t * H + c0 + j8 * 4);
    float4 k4 = *(const float4*)(kk + (size_t)s * H + c0 + j8 * 4);
    float p = q4.x * k4.x * dk[j8*4]   + q4.y * k4.y * dk[j8*4+1]
            + q4.z * k4.z * dk[j8*4+2] + q4.w * k4.w * dk[j8*4+3];
    if (j8 < 4) ah0 += p; else ah1 += p;
  }
  float dd = dist[e];
  float cutv = (dd < 5.0f) ? 0.5f * (__cosf(0.6283185307179586f * dd) + 1.0f) : 0.0f;
  float a0 = sil(ah0) * cutv;
  float a1 = sil(ah1) * cutv;

  float vj[32];
  #pragma unroll
  for (int j8 = 0; j8 < 8; ++j8) {
    float4 v4 = *(const float4*)(vv + (size_t)s * H + c0 + j8 * 4);
    float aa = (j8 < 4) ? a0 : a1;
    vj[j8*4]   = v4.x * dv[j8*4]   * aa;
    vj[j8*4+1] = v4.y * dv[j8*4+1] * aa;
    vj[j8*4+2] = v4.z * dv[j8*4+2] * aa;
    vj[j8*4+3] = v4.w * dv[j8*4+3] * aa;
  }
  __syncthreads();
  #pragma unroll
  for (int j4 = 0; j4 < 8; ++j4) {
    float4 o4 = make_float4(vj[j4*4], vj[j4*4+1], vj[j4*4+2], vj[j4*4+3]);
    *(float4*)(X + lane * TS + c0 + j4 * 4) = o4;
  }
  __syncthreads();

  float acc[32];
  #pragma unroll
  for (int j = 0; j < 32; ++j) acc[j] = bo_att[c0 + j];
  kloop32<128>(Wo_att + c0, H, xr, acc);
  #pragma unroll
  for (int j = 0; j < 32; ++j) vj[j] = sil(acc[j]);
  __syncthreads();
  #pragma unroll
  for (int j4 = 0; j4 < 8; ++j4) {
    float4 o4 = make_float4(vj[j4*4], vj[j4*4+1], vj[j4*4+2], vj[j4*4+3]);
    *(float4*)(X + lane * TS + c0 + j4 * 4) = o4;
  }
  __syncthreads();

  flush_seg(X, Tbuf, s_msg, H, 0);

  int c1 = __builtin_amdgcn_readfirstlane(wave * 64);
  float s0[32], s1[32];
  #pragma unroll
  for (int j = 0; j < 32; ++j) { s0[j] = bs_msg[c1 + j]; s1[j] = bs_msg[c1 + 32 + j]; }
  kloop32x2<128>(Ws_msg + c1, Ws_msg + c1 + 32, 2 * H, xr, s0, s1);
  #pragma unroll
  for (int j = 0; j < 32; ++j) { s0[j] = sil(s0[j]); s1[j] = sil(s1[j]); }

  if (wave < 2) {
    const float4* spp = (const float4*)(sphe + (size_t)e * SPH);
    float4 sa = spp[0], sb = spp[1], sc = spp[2];
    float sp[12] = {sa.x, sa.y, sa.z, sa.w, sb.x, sb.y, sb.z, sb.w, sc.x, sc.y, sc.z, sc.w};
    #pragma unroll
    for (int j = 0; j < 32; ++j) {
      float d = 0.f;
      #pragma unroll
      for (int i = 0; i < 12; ++i) d = fmaf(sp[i], Wsphe[i * H + c1 + j], d);
      s0[j] *= d;
    }
    #pragma unroll
    for (int j = 0; j < 32; ++j) {
      float d = 0.f;
      #pragma unroll
      for (int i = 0; i < 12; ++i) d = fmaf(sp[i], Wsphe[i * H + c1 + 32 + j], d);
      s1[j] *= d;
    }
  } else {
    const float* tpp = tors + (size_t)e * TOR;
    float tp[6];
    #pragma unroll
    for (int i = 0; i < 6; ++i) tp[i] = tpp[i];
    int d0 = c1 - 128;
    #pragma unroll
    for (int j = 0; j < 32; ++j) {
      float d = 0.f;
      #pragma unroll
      for (int i = 0; i < 6; ++i) d = fmaf(tp[i], Wtors[i * H + d0 + j], d);
      s0[j] *= d;
    }
    #pragma unroll
    for (int j = 0; j < 32; ++j) {
      float d = 0.f;
      #pragma unroll
      for (int i = 0; i < 6; ++i) d = fmaf(tp[i], Wtors[i * H + d0 + 32 + j], d);
      s1[j] *= d;
    }
  }
  __syncthreads();

  if (wave < 2) {
    #pragma unroll
    for (int j4 = 0; j4 < 8; ++j4) {
      float4 o4 = make_float4(s0[j4*4], s0[j4*4+1], s0[j4*4+2], s0[j4*4+3]);
      *(float4*)(X + lane * TS + c1 + j4 * 4) = o4;
    }
    #pragma unroll
    for (int j4 = 0; j4 < 8; ++j4) {
      float4 o4 = make_float4(s1[j4*4], s1[j4*4+1], s1[j4*4+2], s1[j4*4+3]);
      *(float4*)(X + lane * TS + c1 + 32 + j4 * 4) = o4;
    }
  }
  __syncthreads();
  flush_seg(X, Tbuf, dsum, 2 * H, 0);
  __syncthreads();

  if (wave >= 2) {
    int cb = c1 - 128;
    #pragma unroll
    for (int j4 = 0; j4 < 8; ++j4) {
      float4 o4 = make_float4(s0[j4*4], s0[j4*4+1], s0[j4*4+2], s0[j4*4+3]);
      *(float4*)(X + lane * TS + cb + j4 * 4) = o4;
    }
    #pragma unroll
    for (int j4 = 0; j4 < 8; ++j4) {
      float4 o4 = make_float4(s1[j4*4], s1[j4*4+1], s1[j4*4+2], s1[j4*4+3]);
      *(float4*)(X + lane * TS + cb + 32 + j4 * 4) = o4;
    }
  }
  __syncthreads();
  flush_seg(X, Tbuf, dsum, 2 * H, 128);
}

// ---------------- edge kernel B: MFMA version ----------------
// wave w owns F N-tiles {w, w+4, 8+w, 12+w, 16+w, 20+w} and output N-tiles {w, w+4}.
__global__ __launch_bounds__(256, 1)
void k_edge_f_mfma(const float* __restrict__ edge_attr,
                   const float* __restrict__ sphe, const float* __restrict__ tors,
                   const ushort_t* __restrict__ wfT_hi, const ushort_t* __restrict__ wfT_lo,
                   const ushort_t* __restrict__ wcatT,
                   const ushort_t* __restrict__ wspheT, const ushort_t* __restrict__ wtorsT,
                   const float* __restrict__ bf, const float* __restrict__ bcat_f,
                   float* __restrict__ out_fji) {
  __shared__ __align__(16) ushort_t SH[64 * 256];   // Ahi | Alo ; union: Y[64][256]
  __shared__ __align__(16) ushort_t SpheL[64 * 32];
  __shared__ __align__(16) ushort_t TorsL[64 * 32];
  ushort_t* AhiL = SH;
  ushort_t* AloL = SH + 8192;

  int tid = threadIdx.x;
  int e0  = blockIdx.x * 64;

  // stage ea -> hi/lo bf16, XOR-swizzled rows
  {
    int r = tid >> 2, qq = tid & 3;
    const float* src = edge_attr + (size_t)(e0 + r) * H + qq * 32;
    u32 swz = (u32)((r & 7) << 4);
    #pragma unroll
    for (int j = 0; j < 8; ++j) {
      float4 x = *(const float4*)(src + j * 4);
      ushort_t h0 = f2bf(x.x), h1 = f2bf(x.y), h2 = f2bf(x.z), h3 = f2bf(x.w);
      union { ushort_t s[4]; u64 u; } P;
      u32 off = ((u32)(r * 256 + (qq * 32 + j * 4) * 2)) ^ swz;
      P.s[0] = h0; P.s[1] = h1; P.s[2] = h2; P.s[3] = h3;
      *(u64*)((char*)AhiL + off) = P.u;
      P.s[0] = f2bf(x.x - bf2f(h0)); P.s[1] = f2bf(x.y - bf2f(h1));
      P.s[2] = f2bf(x.z - bf2f(h2)); P.s[3] = f2bf(x.w - bf2f(h3));
      *(u64*)((char*)AloL + off) = P.u;
    }
  }
  // stage sphe / tors (bf16, zero-pad K=32)
  if (tid < 128) {
    int r = tid & 63;
    bool issp = tid < 64;
    ushort_t vals[32];
    #pragma unroll
    for (int i = 0; i < 32; ++i) vals[i] = 0;
    if (issp) {
      const float* sp = sphe + (size_t)(e0 + r) * SPH;
      #pragma unroll
      for (int i = 0; i < 12; ++i) vals[i] = f2bf(sp[i]);
    } else {
      const float* tp = tors + (size_t)(e0 + r) * TOR;
      #pragma unroll
      for (int i = 0; i < 6; ++i) vals[i] = f2bf(tp[i]);
    }
    ushort_t* dst = issp ? SpheL : TorsL;
    u32 swz = (u32)((r & 7) << 3);
    #pragma unroll
    for (int j = 0; j < 8; ++j) {
      union { ushort_t s[4]; u64 u; } P;
      P.s[0] = vals[j*4]; P.s[1] = vals[j*4+1]; P.s[2] = vals[j*4+2]; P.s[3] = vals[j*4+3];
      u32 off = ((u32)(r * 64 + j * 8)) ^ swz;
      *(u64*)((char*)dst + off) = P.u;
    }
  }
  __syncthreads();

  int lane = tid & 63;
  int w    = tid >> 6;
  int c    = lane & 15;
  int g    = lane >> 4;

  const int ntv[6] = {w, w + 4, 8 + w, 12 + w, 16 + w, 20 + w};

  // GEMM1: F = ea @ Wf, bf16 hi/lo 3-pass
  f32x4 acc[4][6];
  #pragma unroll
  for (int mt = 0; mt < 4; ++mt)
    #pragma unroll
    for (int j = 0; j < 6; ++j) acc[mt][j] = (f32x4){0.f, 0.f, 0.f, 0.f};

  for (int t = 0; t < 4; ++t) {
    bf8 ah[4], al[4];
    #pragma unroll
    for (int mt = 0; mt < 4; ++mt) {
      int row = 16 * mt + c;
      u32 swz = (u32)((row & 7) << 4);
      u32 b0 = ((u32)(row * 256 + t * 64 + g * 8)) ^ swz;
      u32 b1 = ((u32)(row * 256 + t * 64 + 32 + g * 8)) ^ swz;
      ah[mt] = ld_lds_frag((const char*)AhiL, b0, b1);
      al[mt] = ld_lds_frag((const char*)AloL, b0, b1);
    }
    #pragma unroll
    for (int j = 0; j < 6; ++j) {
      int n = 16 * ntv[j] + c;
      bf8 bh = ld_g_frag(wfT_hi + n * 128 + t * 32 + g * 4);
      bf8 bl = ld_g_frag(wfT_lo + n * 128 + t * 32 + g * 4);
      #pragma unroll
      for (int mt = 0; mt < 4; ++mt) {
        acc[mt][j] = __builtin_amdgcn_mfma_f32_16x16x32_bf16(ah[mt], bh, acc[mt][j], 0, 0, 0);
        acc[mt][j] = __builtin_amdgcn_mfma_f32_16x16x32_bf16(al[mt], bh, acc[mt][j], 0, 0, 0);
        acc[mt][j] = __builtin_amdgcn_mfma_f32_16x16x32_bf16(ah[mt], bl, acc[mt][j], 0, 0, 0);
      }
    }
  }
  __syncthreads();   // all waves done reading A; Y may overwrite

  // sphe/tors A-frags
  bf8 spf[4], tof[4];
  #pragma unroll
  for (int mt = 0; mt < 4; ++mt) {
    int row = 16 * mt + c;
    u32 swz = (u32)((row & 7) << 3);
    u32 b0 = ((u32)(row * 64 + g * 8)) ^ swz;
    u32 b1 = ((u32)(row * 64 + 32 + g * 8)) ^ swz;
    spf[mt] = ld_lds_frag((const char*)SpheL, b0, b1);
    tof[mt] = ld_lds_frag((const char*)TorsL, b0, b1);
  }

  // f1: silu, keep in registers
  float sf1[2][4][4];
  #pragma unroll
  for (int jj = 0; jj < 2; ++jj) {
    float bv = bf[16 * ntv[jj] + c];
    #pragma unroll
    for (int mt = 0; mt < 4; ++mt)
      #pragma unroll
      for (int i = 0; i < 4; ++i)
        sf1[jj][mt][i] = sil(acc[mt][jj][i] + bv);
  }
  // f2 * d1 -> Y cols [0,128)
  #pragma unroll
  for (int jj = 0; jj < 2; ++jj) {
    int j = 2 + jj;
    int nf = ntv[j] - 8;
    float bv = bf[16 * ntv[j] + c];
    bf8 wsf = ld_g_frag(wspheT + (16 * nf + c) * 32 + g * 4);
    #pragma unroll
    for (int mt = 0; mt < 4; ++mt) {
      f32x4 dz = (f32x4){0.f, 0.f, 0.f, 0.f};
      f32x4 d1 = __builtin_amdgcn_mfma_f32_16x16x32_bf16(spf[mt], wsf, dz, 0, 0, 0);
      #pragma unroll
      for (int i = 0; i < 4; ++i) {
        float y = sil(acc[mt][j][i] + bv) * d1[i];
        int row = 16 * mt + 4 * g + i;
        int col = 16 * nf + c;
        u32 off = ((u32)(row * 512 + col * 2)) ^ ((u32)((row & 7) << 4));
        *(ushort_t*)((char*)SH + off) = f2bf(y);
      }
    }
  }
  // f3 * d2 -> Y cols [128,256)
  #pragma unroll
  for (int jj = 0; jj < 2; ++jj) {
    int j = 4 + jj;
    int nf = ntv[j] - 16;
    float bv = bf[16 * ntv[j] + c];
    bf8 wtf = ld_g_frag(wtorsT + (16 * nf + c) * 32 + g * 4);
    #pragma unroll
    for (int mt = 0; mt < 4; ++mt) {
      f32x4 dz = (f32x4){0.f, 0.f, 0.f, 0.f};
      f32x4 d2 = __builtin_amdgcn_mfma_f32_16x16x32_bf16(tof[mt], wtf, dz, 0, 0, 0);
      #pragma unroll
      for (int i = 0; i < 4; ++i) {
        float y = sil(acc[mt][j][i] + bv) * d2[i];
        int row = 16 * mt + 4 * g + i;
        int col = 128 + 16 * nf + c;
        u32 off = ((u32)(row * 512 + col * 2)) ^ ((u32)((row & 7) << 4));
        *(ushort_t*)((char*)SH + off) = f2bf(y);
      }
    }
  }
  __syncthreads();

  // GEMM2: out2 = Y(64x256) @ Wcat_f(256x128), single bf16
  f32x4 acc2[4][2];
  #pragma unroll
  for (int mt = 0; mt < 4; ++mt) { acc2[mt][0] = (f32x4){0.f,0.f,0.f,0.f}; acc2[mt][1] = (f32x4){0.f,0.f,0.f,0.f}; }
  const int nt2[2] = {w, w + 4};
  for (int u = 0; u < 8; ++u) {
    bf8 yf[4];
    #pragma unroll
    for (int mt = 0; mt < 4; ++mt) {
      int row = 16 * mt + c;
      u32 swz = (u32)((row & 7) << 4);
      u32 b0 = ((u32)(row * 512 + u * 64 + g * 8)) ^ swz;
      u32 b1 = ((u32)(row * 512 + u * 64 + 32 + g * 8)) ^ swz;
      yf[mt] = ld_lds_frag((const char*)SH, b0, b1);
    }
    #pragma unroll
    for (int jj = 0; jj < 2; ++jj) {
      bf8 bfr = ld_g_frag(wcatT + (16 * nt2[jj] + c) * 256 + u * 32 + g * 4);
      #pragma unroll
      for (int mt = 0; mt < 4; ++mt)
        acc2[mt][jj] = __builtin_amdgcn_mfma_f32_16x16x32_bf16(yf[mt], bfr, acc2[mt][jj], 0, 0, 0);
    }
  }

  // epilogue: f_ji = silu(f1) + silu(out2 + bcat)
  #pragma unroll
  for (int jj = 0; jj < 2; ++jj) {
    float bc = bcat_f[16 * nt2[jj] + c];
    #pragma unroll
    for (int mt = 0; mt < 4; ++mt) {
      #pragma unroll
      for (int i = 0; i < 4; ++i) {
        int row = 16 * mt + 4 * g + i;
        float v = sf1[jj][mt][i] + sil(acc2[mt][jj][i] + bc);
        out_fji[(size_t)(e0 + row) * H + 16 * nt2[jj] + c] = v;
      }
    }
  }
}

// ---------------- d_msg = dsum @ Wcat_msg ----------------
__global__ __launch_bounds__(256, 2)
void k_dmsg(const float* __restrict__ dsum, const float* __restrict__ Wcat_msg,
            float* __restrict__ d_msg) {
  __shared__ float X[64 * 260];
  int tid = threadIdx.x;
  int r0 = blockIdx.x * 64;
  for (int idx = tid; idx < 64 * 64; idx += 256) {
    int r = idx >> 6, seg = idx & 63;
    int row = r0 + r;
    float4 val = make_float4(0.f, 0.f, 0.f, 0.f);
    if (row < NT) val = *(const float4*)(dsum + (size_t)row * 2 * H + seg * 4);
    *(float4*)(X + r * 260 + seg * 4) = val;
  }
  __syncthreads();
  int lane = tid & 63, wave = tid >> 6;
  int c0 = __builtin_amdgcn_readfirstlane(wave * 32);
  float acc[32];
  #pragma unroll
  for (int j = 0; j < 32; ++j) acc[j] = 0.f;
  kloop32<256>(Wcat_msg + c0, H, X + lane * 260, acc);
  int row = r0 + lane;
  if (row < NT) {
    #pragma unroll
    for (int j4 = 0; j4 < 8; ++j4) {
      float4 o4 = make_float4(acc[j4*4], acc[j4*4+1], acc[j4*4+2], acc[j4*4+3]);
      *(float4*)(d_msg + (size_t)row * H + c0 + j4 * 4) = o4;
    }
  }
}

// ---------------- final ----------------
__global__ __launch_bounds__(256, 2)
void k_final(const float* __restrict__ s_msg, const float* __restrict__ x_t,
             const float* __restrict__ d_msg,
             const float* __restrict__ Wo_msg, const float* __restrict__ bo_msg,
             const float* __restrict__ Wfinal, const float* __restrict__ bfinal,
             float* __restrict__ out_ht) {
  __shared__ float SM[64 * TS];
  __shared__ float XT[64 * TS];
  int tid = threadIdx.x;
  int r0 = blockIdx.x * 64;
  for (int idx = tid; idx < 64 * 32; idx += 256) {
    int r = idx >> 5, seg = idx & 31;
    int row = r0 + r;
    float4 v1 = make_float4(0.f, 0.f, 0.f, 0.f), v2 = v1;
    if (row < NT) {
      v1 = *(const float4*)(s_msg + (size_t)row * H + seg * 4);
      v2 = *(const float4*)(x_t   + (size_t)row * H + seg * 4);
    }
    *(float4*)(SM + r * TS + seg * 4) = v1;
    *(float4*)(XT + r * TS + seg * 4) = v2;
  }
  __syncthreads();
  int lane = tid & 63, wave = tid >> 6;
  int c0 = __builtin_amdgcn_readfirstlane(wave * 32);
  int row = r0 + lane;
  float acc1[32], acc2[32];
  #pragma unroll
  for (int j = 0; j < 32; ++j) { acc1[j] = bo_msg[c0 + j]; acc2[j] = bo_msg[H + c0 + j]; }
  kloop32x2<128>(Wo_msg + c0, Wo_msg + H + c0, 2 * H, SM + lane * TS, acc1, acc2);
  float z[32];
  if (row < NT) {
    #pragma unroll
    for (int j4 = 0; j4 < 8; ++j4) {
      float4 dm = *(const float4*)(d_msg + (size_t)row * H + c0 + j4 * 4);
      z[j4*4]   = acc1[j4*4]   + acc2[j4*4]   * dm.x;
      z[j4*4+1] = acc1[j4*4+1] + acc2[j4*4+1] * dm.y;
      z[j4*4+2] = acc1[j4*4+2] + acc2[j4*4+2] * dm.z;
      z[j4*4+3] = acc1[j4*4+3] + acc2[j4*4+3] * dm.w;
    }
  } else {
    #pragma unroll
    for (int j = 0; j < 32; ++j) z[j] = 0.f;
  }
  __syncthreads();
  #pragma unroll
  for (int j4 = 0; j4 < 8; ++j4) {
    float4 o4 = make_float4(z[j4*4], z[j4*4+1], z[j4*4+2], z[j4*4+3]);
    *(float4*)(SM + lane * TS + c0 + j4 * 4) = o4;
  }
  __syncthreads();
  float acc[32];
  #pragma unroll
  for (int j = 0; j < 32; ++j) acc[j] = bfinal[c0 + j];
  kloop32<128>(Wfinal + c0, H, XT + lane * TS, acc);
  kloop32<128>(Wfinal + H * H + c0, H, SM + lane * TS, acc);
  if (row < NT) {
    #pragma unroll
    for (int j4 = 0; j4 < 8; ++j4) {
      float4 o4 = make_float4(sil(acc[j4*4]), sil(acc[j4*4+1]), sil(acc[j4*4+2]), sil(acc[j4*4+3]));
      *(float4*)(out_ht + (size_t)row * H + c0 + j4 * 4) = o4;
    }
  }
}

extern "C" void kernel_launch(void* const* d_in, const int* in_sizes, int n_in,
                              void* d_out, int out_size, void* d_ws, size_t ws_size,
                              hipStream_t stream) {
  const float* x_s       = (const float*)d_in[0];
  const float* x_t       = (const float*)d_in[1];
  const int*   ei        = (const int*)  d_in[2];
  const float* edge_attr = (const float*)d_in[3];
  const float* sphe      = (const float*)d_in[4];
  const float* tors      = (const float*)d_in[5];
  const float* dist      = (const float*)d_in[6];
  const float* Ws1       = (const float*)d_in[7];
  const float* Ws2       = (const float*)d_in[8];
  const float* Wt1       = (const float*)d_in[9];
  const float* Wt2       = (const float*)d_in[10];
  const float* Wq        = (const float*)d_in[11];
  const float* bq        = (const float*)d_in[12];
  const float* Wk        = (const float*)d_in[13];
  const float* bk        = (const float*)d_in[14];
  const float* Wv        = (const float*)d_in[15];
  const float* bv        = (const float*)d_in[16];
  const float* Wdk       = (const float*)d_in[17];
  const float* bdk       = (const float*)d_in[18];
  const float* Wdv       = (const float*)d_in[19];
  const float* bdv       = (const float*)d_in[20];
  const float* Wo_att    = (const float*)d_in[21];
  const float* bo_att    = (const float*)d_in[22];
  const float* Ws_msg    = (const float*)d_in[23];
  const float* bs_msg    = (const float*)d_in[24];
  const float* Wcat_msg  = (const float*)d_in[25];
  const float* Wo_msg    = (const float*)d_in[26];
  const float* bo_msg    = (const float*)d_in[27];
  const float* Wfinal    = (const float*)d_in[28];
  const float* bfinal    = (const float*)d_in[29];
  const float* Wf        = (const float*)d_in[30];
  const float* bf        = (const float*)d_in[31];
  const float* Wcat_f    = (const float*)d_in[32];
  const float* bcat_f    = (const float*)d_in[33];

  float* ws = (float*)d_ws;
  float* qbuf  = ws;                         // NT*H
  float* kbuf  = qbuf  + (size_t)NT * H;     // NS*H
  float* vbuf  = kbuf  + (size_t)NS * H;     // NS*H
  float* smsg  = vbuf  + (size_t)NS * H;     // NT*H
  float* dsum  = smsg  + (size_t)NT * H;     // NT*2H
  float* dmsg  = dsum  + (size_t)NT * 2 * H; // NT*H
  float* wsphe = dmsg  + (size_t)NT * H;     // 12*128
  float* wtors = wsphe + SPH * H;            // 6*128
  int*   deg    = (int*)(wtors + TOR * H);   // NT
  int*   cursor = deg + NT;                  // NT
  int*   perm   = cursor + NT;               // EDG
  ushort_t* wfT_hi = (ushort_t*)(perm + EDG);     // 384*128
  ushort_t* wfT_lo = wfT_hi + 384 * 128;          // 384*128
  ushort_t* wcatT  = wfT_lo + 384 * 128;          // 128*256
  ushort_t* wspheT = wcatT + 128 * 256;           // 128*32
  ushort_t* wtorsT = wspheT + 128 * 32;           // 128*32

  float* out_ht  = (float*)d_out;
  float* out_fji = out_ht + (size_t)NT * H;

  hipMemsetAsync(smsg, 0, (size_t)NT * H * sizeof(float), stream);
  hipMemsetAsync(dsum, 0, (size_t)NT * 2 * H * sizeof(float), stream);
  hipMemsetAsync(deg, 0, (size_t)NT * sizeof(int), stream);

  k_hist<<<(EDG + 255) / 256, 256, 0, stream>>>(ei, deg);
  k_scan<<<1, 256, 0, stream>>>(deg, cursor);
  k_scatter<<<(EDG + 255) / 256, 256, 0, stream>>>(ei, cursor, perm);

  k_smallw<<<1, 256, 0, stream>>>(Ws1, Ws2, Wt1, Wt2, wsphe, wtors);
  k_prepw<<<(384 * 128 + 255) / 256, 256, 0, stream>>>(Wf, Wcat_f, Ws1, Ws2, Wt1, Wt2,
                                                       wfT_hi, wfT_lo, wcatT, wspheT, wtorsT);

  int nblk = (NT + 63) / 64;
  k_gemm128<<<nblk, 256, 0, stream>>>(x_t, Wq, bq, qbuf, NT);
  k_gemm128<<<nblk, 256, 0, stream>>>(x_s, Wk, bk, kbuf, NS);
  k_gemm128<<<nblk, 256, 0, stream>>>(x_s, Wv, bv, vbuf, NS);

  k_edge_attn<<<EDG / 64, 256, 0, stream>>>(edge_attr, ei, perm, sphe, tors, dist,
                                            qbuf, kbuf, vbuf,
                                            Wdk, bdk, Wdv, bdv, Wo_att, bo_att,
                                            Ws_msg, bs_msg, wsphe, wtors,
                                            smsg, dsum);

  k_edge_f_mfma<<<EDG / 64, 256, 0, stream>>>(edge_attr, sphe, tors,
                                              wfT_hi, wfT_lo, wcatT, wspheT, wtorsT,
                                              bf, bcat_f, out_fji);

  k_dmsg<<<nblk, 256, 0, stream>>>(dsum, Wcat_msg, dmsg);

  k_final<<<nblk, 256, 0, stream>>>(smsg, x_t, dmsg, Wo_msg, bo_msg,
                                    Wfinal, bfinal, out_ht);
}

// Round 8
// 1720.093 us; speedup vs baseline: 4.9644x; 1.2228x over previous
//
#include <hip/hip_runtime.h>
#include <math.h>

static constexpr int H    = 128;
static constexpr int MID  = 64;
static constexpr int NS   = 20000;
static constexpr int NT   = 20000;
static constexpr int EDG  = 320000;
static constexpr int SPH  = 12;
static constexpr int TOR  = 6;
static constexpr int TS   = 132; // LDS row stride (floats)

typedef unsigned long long u64;
typedef unsigned int u32;
typedef unsigned short ushort_t;

using bf8   = __attribute__((ext_vector_type(8))) short;
using f32x4 = __attribute__((ext_vector_type(4))) float;

__device__ __forceinline__ float sil(float x) {
  return x / (1.0f + __expf(-x));
}

__device__ __forceinline__ ushort_t f2bf(float x) {
  u32 u = __float_as_uint(x);
  u32 r = u + 0x7FFFu + ((u >> 16) & 1u);
  return (ushort_t)(r >> 16);
}
__device__ __forceinline__ float bf2f(ushort_t h) {
  return __uint_as_float(((u32)h) << 16);
}

__device__ __forceinline__ bf8 ld_lds_frag(const char* base, u32 b0, u32 b1) {
  union { u64 u[2]; bf8 v; } X;
  X.u[0] = *(const u64*)(base + b0);
  X.u[1] = *(const u64*)(base + b1);
  return X.v;
}
__device__ __forceinline__ bf8 ld_g_frag(const ushort_t* p) {
  union { u64 u[2]; bf8 v; } X;
  X.u[0] = *(const u64*)(p);
  X.u[1] = *(const u64*)(p + 16);
  return X.v;
}

// acc[32] += sum_i xr[i] * W[i*ldw + j]  (kept for node GEMM / dmsg / final)
template<int K>
__device__ __forceinline__ void kloop32(const float* __restrict__ W, int ldw,
                                        const float* xr, float* acc) {
  #pragma unroll 2
  for (int i0 = 0; i0 < K; i0 += 4) {
    float4 a4 = *(const float4*)(xr + i0);
    const float* w = W + i0 * ldw;
    #pragma unroll
    for (int j = 0; j < 32; ++j) acc[j] = fmaf(a4.x, w[j], acc[j]);
    w += ldw;
    #pragma unroll
    for (int j = 0; j < 32; ++j) acc[j] = fmaf(a4.y, w[j], acc[j]);
    w += ldw;
    #pragma unroll
    for (int j = 0; j < 32; ++j) acc[j] = fmaf(a4.z, w[j], acc[j]);
    w += ldw;
    #pragma unroll
    for (int j = 0; j < 32; ++j) acc[j] = fmaf(a4.w, w[j], acc[j]);
  }
}

template<int K>
__device__ __forceinline__ void kloop32x2(const float* __restrict__ Wa,
                                          const float* __restrict__ Wb, int ldw,
                                          const float* xr, float* acca, float* accb) {
  #pragma unroll 2
  for (int i0 = 0; i0 < K; i0 += 4) {
    float4 a4 = *(const float4*)(xr + i0);
    float av[4] = {a4.x, a4.y, a4.z, a4.w};
    #pragma unroll
    for (int u = 0; u < 4; ++u) {
      const float* wa = Wa + (i0 + u) * ldw;
      const float* wb = Wb + (i0 + u) * ldw;
      #pragma unroll
      for (int j = 0; j < 32; ++j) acca[j] = fmaf(av[u], wa[j], acca[j]);
      #pragma unroll
      for (int j = 0; j < 32; ++j) accb[j] = fmaf(av[u], wb[j], accb[j]);
    }
  }
}

// segmented flush over sorted targets; X stride = TS floats
__device__ __forceinline__ void flush_seg(const float* __restrict__ X,
                                          const int* __restrict__ Tbuf,
                                          float* __restrict__ out, int ldo, int colbase) {
  int c  = threadIdx.x & 127;
  int r0 = (threadIdx.x >> 7) * 32;
  float acc = X[r0 * TS + c];
  int tcur = Tbuf[r0];
  #pragma unroll 4
  for (int r = r0 + 1; r < r0 + 32; ++r) {
    float v = X[r * TS + c];
    int tn = Tbuf[r];
    if (tn != tcur) {
      atomicAdd(&out[(size_t)tcur * ldo + colbase + c], acc);
      acc = v; tcur = tn;
    } else {
      acc += v;
    }
  }
  atomicAdd(&out[(size_t)tcur * ldo + colbase + c], acc);
}

// ---------------- counting sort ----------------
__global__ void k_hist(const int* __restrict__ ei, int* __restrict__ deg) {
  int e = blockIdx.x * 256 + threadIdx.x;
  if (e < EDG) atomicAdd(&deg[ei[EDG + e]], 1);
}

__global__ void k_scan(const int* __restrict__ deg, int* __restrict__ cursor) {
  __shared__ int part[256];
  int tid = threadIdx.x;
  const int PER = (NT + 255) / 256;
  int base = tid * PER;
  int sum = 0;
  for (int i = 0; i < PER; ++i) {
    int idx = base + i;
    if (idx < NT) sum += deg[idx];
  }
  part[tid] = sum;
  __syncthreads();
  if (tid == 0) {
    int acc = 0;
    for (int i = 0; i < 256; ++i) { int v = part[i]; part[i] = acc; acc += v; }
  }
  __syncthreads();
  int acc = part[tid];
  for (int i = 0; i < PER; ++i) {
    int idx = base + i;
    if (idx < NT) { cursor[idx] = acc; acc += deg[idx]; }
  }
}

__global__ void k_scatter(const int* __restrict__ ei, int* __restrict__ cursor,
                          int* __restrict__ perm) {
  int e = blockIdx.x * 256 + threadIdx.x;
  if (e < EDG) {
    int t = ei[EDG + e];
    int pos = atomicAdd(&cursor[t], 1);
    perm[pos] = e;
  }
}

// ---------------- weight prep: transposed bf16 (hi/lo) ----------------
__global__ void k_prepw(const float* __restrict__ Wf, const float* __restrict__ Wcat_f,
                        const float* __restrict__ Ws1, const float* __restrict__ Ws2,
                        const float* __restrict__ Wt1, const float* __restrict__ Wt2,
                        const float* __restrict__ Wdk, const float* __restrict__ Wdv,
                        const float* __restrict__ Wo_att, const float* __restrict__ Ws_msg,
                        ushort_t* __restrict__ wfT_hi, ushort_t* __restrict__ wfT_lo,
                        ushort_t* __restrict__ wcatT,
                        ushort_t* __restrict__ wspheT, ushort_t* __restrict__ wtorsT,
                        ushort_t* __restrict__ wdkT_hi, ushort_t* __restrict__ wdkT_lo,
                        ushort_t* __restrict__ wdvT_hi, ushort_t* __restrict__ wdvT_lo,
                        ushort_t* __restrict__ woT_hi, ushort_t* __restrict__ woT_lo,
                        ushort_t* __restrict__ wsmT_hi, ushort_t* __restrict__ wsmT_lo) {
  int idx = blockIdx.x * 256 + threadIdx.x;
  if (idx < 384 * 128) {                 // wfT[n][k] = Wf[k][n], hi/lo
    int n = idx >> 7, k = idx & 127;
    float v = Wf[k * 384 + n];
    ushort_t h = f2bf(v);
    wfT_hi[idx] = h;
    wfT_lo[idx] = f2bf(v - bf2f(h));
  }
  if (idx < 128 * 256) {                 // wcatT[n][k] = Wcat_f[k][n]
    int n = idx >> 8, k = idx & 255;
    wcatT[idx] = f2bf(Wcat_f[k * 128 + n]);
  }
  if (idx < 128 * 32) {                  // wspheT / wtorsT [n][k], k zero-padded to 32
    int n = idx >> 5, k = idx & 31;
    float v = 0.f;
    if (k < SPH) {
      for (int m = 0; m < MID; ++m) v = fmaf(Ws1[k * MID + m], Ws2[m * H + n], v);
    }
    wspheT[idx] = f2bf(v);
    float v2 = 0.f;
    if (k < TOR) {
      for (int m = 0; m < MID; ++m) v2 = fmaf(Wt1[k * MID + m], Wt2[m * H + n], v2);
    }
    wtorsT[idx] = f2bf(v2);
  }
  if (idx < 128 * 128) {                 // wdkT / wdvT / woT [n][k] hi/lo
    int n = idx >> 7, k = idx & 127;
    float v = Wdk[k * H + n];
    ushort_t h = f2bf(v);
    wdkT_hi[idx] = h; wdkT_lo[idx] = f2bf(v - bf2f(h));
    v = Wdv[k * H + n];
    h = f2bf(v);
    wdvT_hi[idx] = h; wdvT_lo[idx] = f2bf(v - bf2f(h));
    v = Wo_att[k * H + n];
    h = f2bf(v);
    woT_hi[idx] = h; woT_lo[idx] = f2bf(v - bf2f(h));
  }
  if (idx < 256 * 128) {                 // wsmT[n][k] = Ws_msg[k*256+n] hi/lo
    int n = idx >> 7, k = idx & 127;
    float v = Ws_msg[k * 256 + n];
    ushort_t h = f2bf(v);
    wsmT_hi[idx] = h; wsmT_lo[idx] = f2bf(v - bf2f(h));
  }
}

// ---------------- node GEMM ----------------
__global__ __launch_bounds__(256, 4)
void k_gemm128(const float* __restrict__ A, const float* __restrict__ W,
               const float* __restrict__ bias, float* __restrict__ Out, int M) {
  __shared__ float X[64 * TS];
  int tid = threadIdx.x;
  int r0 = blockIdx.x * 64;
  for (int idx = tid; idx < 64 * 32; idx += 256) {
    int r = idx >> 5, seg = idx & 31;
    int row = r0 + r;
    float4 val = make_float4(0.f, 0.f, 0.f, 0.f);
    if (row < M) val = *(const float4*)(A + row * H + seg * 4);
    *(float4*)(X + r * TS + seg * 4) = val;
  }
  __syncthreads();
  int lane = tid & 63, wave = tid >> 6;
  int c0 = __builtin_amdgcn_readfirstlane(wave * 32);
  float acc[32];
  #pragma unroll
  for (int j = 0; j < 32; ++j) acc[j] = bias[c0 + j];
  kloop32<128>(W + c0, H, X + lane * TS, acc);
  int row = r0 + lane;
  if (row < M) {
    #pragma unroll
    for (int j4 = 0; j4 < 8; ++j4) {
      float4 o4 = make_float4(acc[j4*4], acc[j4*4+1], acc[j4*4+2], acc[j4*4+3]);
      *(float4*)(Out + row * H + c0 + j4 * 4) = o4;
    }
  }
}

// ---------------- edge kernel A: MFMA version ----------------
// 64 sorted edges/block. Wave w owns col-tiles {2w,2w+1} for DK/DV/Wo_att (cols [32w,32w+32)),
// and tiles {w,4+w,8+w,12+w} of the 256-wide Ws_msg output.
__global__ __launch_bounds__(256, 2)
void k_edge_attn_mfma(const float* __restrict__ edge_attr, const int* __restrict__ ei,
                      const int* __restrict__ perm,
                      const float* __restrict__ sphe, const float* __restrict__ tors,
                      const float* __restrict__ dist,
                      const float* __restrict__ q, const float* __restrict__ kk,
                      const float* __restrict__ vv,
                      const ushort_t* __restrict__ wdkT_hi, const ushort_t* __restrict__ wdkT_lo,
                      const ushort_t* __restrict__ wdvT_hi, const ushort_t* __restrict__ wdvT_lo,
                      const ushort_t* __restrict__ woT_hi, const ushort_t* __restrict__ woT_lo,
                      const ushort_t* __restrict__ wsmT_hi, const ushort_t* __restrict__ wsmT_lo,
                      const ushort_t* __restrict__ wspheT, const ushort_t* __restrict__ wtorsT,
                      const float* __restrict__ bdk, const float* __restrict__ bdv,
                      const float* __restrict__ bo_att, const float* __restrict__ bs_msg,
                      float* __restrict__ s_msg, float* __restrict__ dsum) {
  __shared__ __align__(16) ushort_t AHs[8192];   // hi bf16 of current GEMM A (64x128)
  __shared__ __align__(16) ushort_t ALs[8192];   // lo bf16
  __shared__ __align__(16) float Bb[64 * TS];    // f32 staging: dk, then v_j, then d_ji halves
  __shared__ float ATT[64 * 8];                  // attn per (edge, head)
  __shared__ __align__(16) ushort_t SpheL[2048];
  __shared__ __align__(16) ushort_t TorsL[2048];
  __shared__ int Ebuf[64], Tbuf[64], Sbuf[64];

  int tid = threadIdx.x;
  int b0i = blockIdx.x * 64;
  if (tid < 64) {
    int ee = perm[b0i + tid];
    Ebuf[tid] = ee;
    Tbuf[tid] = ei[EDG + ee];
    Sbuf[tid] = ei[ee];
  }
  __syncthreads();

  // stage ea (gathered) -> hi/lo bf16, XOR-swizzled
  {
    int r = tid >> 2, qq = tid & 3;
    const float* src = edge_attr + (size_t)Ebuf[r] * H + qq * 32;
    u32 swz = (u32)((r & 7) << 4);
    #pragma unroll
    for (int j = 0; j < 8; ++j) {
      float4 x = *(const float4*)(src + j * 4);
      ushort_t h0 = f2bf(x.x), h1 = f2bf(x.y), h2 = f2bf(x.z), h3 = f2bf(x.w);
      union { ushort_t s[4]; u64 u; } P;
      u32 off = ((u32)(r * 256 + (qq * 32 + j * 4) * 2)) ^ swz;
      P.s[0] = h0; P.s[1] = h1; P.s[2] = h2; P.s[3] = h3;
      *(u64*)((char*)AHs + off) = P.u;
      P.s[0] = f2bf(x.x - bf2f(h0)); P.s[1] = f2bf(x.y - bf2f(h1));
      P.s[2] = f2bf(x.z - bf2f(h2)); P.s[3] = f2bf(x.w - bf2f(h3));
      *(u64*)((char*)ALs + off) = P.u;
    }
  }
  // stage sphe/tors (gathered, zero-padded K=32)
  if (tid < 128) {
    int r = tid & 63;
    bool issp = tid < 64;
    ushort_t vals[32];
    #pragma unroll
    for (int i = 0; i < 32; ++i) vals[i] = 0;
    if (issp) {
      const float* sp = sphe + (size_t)Ebuf[r] * SPH;
      #pragma unroll
      for (int i = 0; i < 12; ++i) vals[i] = f2bf(sp[i]);
    } else {
      const float* tp = tors + (size_t)Ebuf[r] * TOR;
      #pragma unroll
      for (int i = 0; i < 6; ++i) vals[i] = f2bf(tp[i]);
    }
    ushort_t* dst = issp ? SpheL : TorsL;
    u32 swz = (u32)((r & 7) << 3);
    #pragma unroll
    for (int j = 0; j < 8; ++j) {
      union { ushort_t s[4]; u64 u; } P;
      P.s[0] = vals[j*4]; P.s[1] = vals[j*4+1]; P.s[2] = vals[j*4+2]; P.s[3] = vals[j*4+3];
      u32 off = ((u32)(r * 64 + j * 8)) ^ swz;
      *(u64*)((char*)dst + off) = P.u;
    }
  }
  __syncthreads();

  int lane = tid & 63, w = tid >> 6;
  int c = lane & 15, g = lane >> 4;

  // ---- GEMM1 (dual): DK = ea@Wdk, DV = ea@Wdv, hi/lo 3-pass ----
  f32x4 ak[4][2], av[4][2];
  #pragma unroll
  for (int mt = 0; mt < 4; ++mt)
    #pragma unroll
    for (int jj = 0; jj < 2; ++jj) {
      ak[mt][jj] = (f32x4){0.f,0.f,0.f,0.f};
      av[mt][jj] = (f32x4){0.f,0.f,0.f,0.f};
    }
  for (int t = 0; t < 4; ++t) {
    bf8 ah[4], al[4];
    #pragma unroll
    for (int mt = 0; mt < 4; ++mt) {
      int row = 16 * mt + c;
      u32 swz = (u32)((row & 7) << 4);
      u32 o0 = ((u32)(row * 256 + t * 64 + g * 8)) ^ swz;
      u32 o1 = ((u32)(row * 256 + t * 64 + 32 + g * 8)) ^ swz;
      ah[mt] = ld_lds_frag((const char*)AHs, o0, o1);
      al[mt] = ld_lds_frag((const char*)ALs, o0, o1);
    }
    #pragma unroll
    for (int jj = 0; jj < 2; ++jj) {
      int n = 16 * (2 * w + jj) + c;
      const ushort_t* pk = wdkT_hi + n * 128 + t * 32 + g * 4;
      const ushort_t* pkl = wdkT_lo + n * 128 + t * 32 + g * 4;
      const ushort_t* pv = wdvT_hi + n * 128 + t * 32 + g * 4;
      const ushort_t* pvl = wdvT_lo + n * 128 + t * 32 + g * 4;
      bf8 bhk = ld_g_frag(pk), blk = ld_g_frag(pkl);
      bf8 bhv = ld_g_frag(pv), blv = ld_g_frag(pvl);
      #pragma unroll
      for (int mt = 0; mt < 4; ++mt) {
        ak[mt][jj] = __builtin_amdgcn_mfma_f32_16x16x32_bf16(ah[mt], bhk, ak[mt][jj], 0, 0, 0);
        ak[mt][jj] = __builtin_amdgcn_mfma_f32_16x16x32_bf16(al[mt], bhk, ak[mt][jj], 0, 0, 0);
        ak[mt][jj] = __builtin_amdgcn_mfma_f32_16x16x32_bf16(ah[mt], blk, ak[mt][jj], 0, 0, 0);
        av[mt][jj] = __builtin_amdgcn_mfma_f32_16x16x32_bf16(ah[mt], bhv, av[mt][jj], 0, 0, 0);
        av[mt][jj] = __builtin_amdgcn_mfma_f32_16x16x32_bf16(al[mt], bhv, av[mt][jj], 0, 0, 0);
        av[mt][jj] = __builtin_amdgcn_mfma_f32_16x16x32_bf16(ah[mt], blv, av[mt][jj], 0, 0, 0);
      }
    }
  }
  // DK epilogue -> Bb (wave-local cols [32w,32w+32))
  #pragma unroll
  for (int jj = 0; jj < 2; ++jj) {
    int col = 32 * w + 16 * jj + c;
    float bv = bdk[col];
    #pragma unroll
    for (int mt = 0; mt < 4; ++mt)
      #pragma unroll
      for (int i = 0; i < 4; ++i)
        Bb[(16 * mt + 4 * g + i) * TS + col] = sil(ak[mt][jj][i] + bv);
  }

  // ---- attn phase (row-per-lane; wave w covers cols [32w,32w+32) = heads 2w,2w+1) ----
  {
    int e = Ebuf[lane], tt = Tbuf[lane], ss = Sbuf[lane];
    int c0 = w * 32;
    float ah0 = 0.f, ah1 = 0.f;
    #pragma unroll
    for (int j8 = 0; j8 < 8; ++j8) {
      float4 q4 = *(const float4*)(q  + (size_t)tt * H + c0 + j8 * 4);
      float4 k4 = *(const float4*)(kk + (size_t)ss * H + c0 + j8 * 4);
      float4 d4 = *(const float4*)(Bb + lane * TS + c0 + j8 * 4);
      float p = q4.x * k4.x * d4.x + q4.y * k4.y * d4.y
              + q4.z * k4.z * d4.z + q4.w * k4.w * d4.w;
      if (j8 < 4) ah0 += p; else ah1 += p;
    }
    float dd = dist[e];
    float cutv = (dd < 5.0f) ? 0.5f * (__cosf(0.6283185307179586f * dd) + 1.0f) : 0.0f;
    ATT[lane * 8 + 2 * w]     = sil(ah0) * cutv;
    ATT[lane * 8 + 2 * w + 1] = sil(ah1) * cutv;
  }
  __syncthreads();   // all waves done with GEMM1 reads of AHs/ALs

  // ---- DV epilogue: vjpre = silu(DV+b) * attn * v[src] -> AHs/ALs (hi/lo) ----
  #pragma unroll
  for (int jj = 0; jj < 2; ++jj) {
    int col = 32 * w + 16 * jj + c;
    float bv = bdv[col];
    #pragma unroll
    for (int mt = 0; mt < 4; ++mt) {
      #pragma unroll
      for (int i = 0; i < 4; ++i) {
        int row = 16 * mt + 4 * g + i;
        float att = ATT[row * 8 + 2 * w + jj];
        float vval = vv[(size_t)Sbuf[row] * H + col];
        float y = sil(av[mt][jj][i] + bv) * att * vval;
        ushort_t h = f2bf(y);
        u32 off = ((u32)(row * 256 + col * 2)) ^ ((u32)((row & 7) << 4));
        *(ushort_t*)((char*)AHs + off) = h;
        *(ushort_t*)((char*)ALs + off) = f2bf(y - bf2f(h));
      }
    }
  }
  __syncthreads();

  // ---- GEMM2: v_j_pre = vjpre @ Wo_att, 3-pass ----
  f32x4 a2[4][2];
  #pragma unroll
  for (int mt = 0; mt < 4; ++mt) { a2[mt][0] = (f32x4){0.f,0.f,0.f,0.f}; a2[mt][1] = (f32x4){0.f,0.f,0.f,0.f}; }
  for (int t = 0; t < 4; ++t) {
    bf8 ah[4], al[4];
    #pragma unroll
    for (int mt = 0; mt < 4; ++mt) {
      int row = 16 * mt + c;
      u32 swz = (u32)((row & 7) << 4);
      u32 o0 = ((u32)(row * 256 + t * 64 + g * 8)) ^ swz;
      u32 o1 = ((u32)(row * 256 + t * 64 + 32 + g * 8)) ^ swz;
      ah[mt] = ld_lds_frag((const char*)AHs, o0, o1);
      al[mt] = ld_lds_frag((const char*)ALs, o0, o1);
    }
    #pragma unroll
    for (int jj = 0; jj < 2; ++jj) {
      int n = 16 * (2 * w + jj) + c;
      bf8 bh = ld_g_frag(woT_hi + n * 128 + t * 32 + g * 4);
      bf8 bl = ld_g_frag(woT_lo + n * 128 + t * 32 + g * 4);
      #pragma unroll
      for (int mt = 0; mt < 4; ++mt) {
        a2[mt][jj] = __builtin_amdgcn_mfma_f32_16x16x32_bf16(ah[mt], bh, a2[mt][jj], 0, 0, 0);
        a2[mt][jj] = __builtin_amdgcn_mfma_f32_16x16x32_bf16(al[mt], bh, a2[mt][jj], 0, 0, 0);
        a2[mt][jj] = __builtin_amdgcn_mfma_f32_16x16x32_bf16(ah[mt], bl, a2[mt][jj], 0, 0, 0);
      }
    }
  }
  __syncthreads();   // all GEMM2 reads done before AHs/ALs overwrite

  // epilogue: v_j = silu(.) -> Bb (f32 for flush) + AHs/ALs (hi/lo for GEMM3)
  #pragma unroll
  for (int jj = 0; jj < 2; ++jj) {
    int col = 32 * w + 16 * jj + c;
    float bv = bo_att[col];
    #pragma unroll
    for (int mt = 0; mt < 4; ++mt) {
      #pragma unroll
      for (int i = 0; i < 4; ++i) {
        int row = 16 * mt + 4 * g + i;
        float y = sil(a2[mt][jj][i] + bv);
        Bb[row * TS + col] = y;
        ushort_t h = f2bf(y);
        u32 off = ((u32)(row * 256 + col * 2)) ^ ((u32)((row & 7) << 4));
        *(ushort_t*)((char*)AHs + off) = h;
        *(ushort_t*)((char*)ALs + off) = f2bf(y - bf2f(h));
      }
    }
  }
  __syncthreads();

  flush_seg(Bb, Tbuf, s_msg, H, 0);

  // ---- GEMM3: S = v_j @ Ws_msg (N=256), 3-pass; wave tiles {w,4+w,8+w,12+w} ----
  const int nt3[4] = {w, 4 + w, 8 + w, 12 + w};
  f32x4 a3[4][4];
  #pragma unroll
  for (int mt = 0; mt < 4; ++mt)
    #pragma unroll
    for (int jj = 0; jj < 4; ++jj) a3[mt][jj] = (f32x4){0.f,0.f,0.f,0.f};
  for (int t = 0; t < 4; ++t) {
    bf8 ah[4], al[4];
    #pragma unroll
    for (int mt = 0; mt < 4; ++mt) {
      int row = 16 * mt + c;
      u32 swz = (u32)((row & 7) << 4);
      u32 o0 = ((u32)(row * 256 + t * 64 + g * 8)) ^ swz;
      u32 o1 = ((u32)(row * 256 + t * 64 + 32 + g * 8)) ^ swz;
      ah[mt] = ld_lds_frag((const char*)AHs, o0, o1);
      al[mt] = ld_lds_frag((const char*)ALs, o0, o1);
    }
    #pragma unroll
    for (int jj = 0; jj < 4; ++jj) {
      int n = 16 * nt3[jj] + c;
      bf8 bh = ld_g_frag(wsmT_hi + n * 128 + t * 32 + g * 4);
      bf8 bl = ld_g_frag(wsmT_lo + n * 128 + t * 32 + g * 4);
      #pragma unroll
      for (int mt = 0; mt < 4; ++mt) {
        a3[mt][jj] = __builtin_amdgcn_mfma_f32_16x16x32_bf16(ah[mt], bh, a3[mt][jj], 0, 0, 0);
        a3[mt][jj] = __builtin_amdgcn_mfma_f32_16x16x32_bf16(al[mt], bh, a3[mt][jj], 0, 0, 0);
        a3[mt][jj] = __builtin_amdgcn_mfma_f32_16x16x32_bf16(ah[mt], bl, a3[mt][jj], 0, 0, 0);
      }
    }
  }

  // sphe/tors A-frags for d1/d2
  bf8 spf[4], tof[4];
  #pragma unroll
  for (int mt = 0; mt < 4; ++mt) {
    int row = 16 * mt + c;
    u32 swz = (u32)((row & 7) << 3);
    u32 o0 = ((u32)(row * 64 + g * 8)) ^ swz;
    u32 o1 = ((u32)(row * 64 + 32 + g * 8)) ^ swz;
    spf[mt] = ld_lds_frag((const char*)SpheL, o0, o1);
    tof[mt] = ld_lds_frag((const char*)TorsL, o0, o1);
  }

  // Round A: d_ji cols [0,128): tiles {w,4+w} with d1
  __syncthreads();   // flush reads of Bb complete
  #pragma unroll
  for (int jj = 0; jj < 2; ++jj) {
    int tj = nt3[jj];
    int col = 16 * tj + c;
    float bv = bs_msg[col];
    bf8 wsf = ld_g_frag(wspheT + col * 32 + g * 4);
    #pragma unroll
    for (int mt = 0; mt < 4; ++mt) {
      f32x4 dz = (f32x4){0.f,0.f,0.f,0.f};
      f32x4 d1 = __builtin_amdgcn_mfma_f32_16x16x32_bf16(spf[mt], wsf, dz, 0, 0, 0);
      #pragma unroll
      for (int i = 0; i < 4; ++i) {
        int row = 16 * mt + 4 * g + i;
        Bb[row * TS + col] = sil(a3[mt][jj][i] + bv) * d1[i];
      }
    }
  }
  __syncthreads();
  flush_seg(Bb, Tbuf, dsum, 2 * H, 0);
  __syncthreads();

  // Round B: d_ji cols [128,256): tiles {8+w,12+w} with d2
  #pragma unroll
  for (int jj = 2; jj < 4; ++jj) {
    int tj = nt3[jj];
    int gcol = 16 * tj + c;           // 128..255
    float bv = bs_msg[gcol];
    bf8 wtf = ld_g_frag(wtorsT + (gcol - 128) * 32 + g * 4);
    #pragma unroll
    for (int mt = 0; mt < 4; ++mt) {
      f32x4 dz = (f32x4){0.f,0.f,0.f,0.f};
      f32x4 d2 = __builtin_amdgcn_mfma_f32_16x16x32_bf16(tof[mt], wtf, dz, 0, 0, 0);
      #pragma unroll
      for (int i = 0; i < 4; ++i) {
        int row = 16 * mt + 4 * g + i;
        Bb[row * TS + (gcol - 128)] = sil(a3[mt][jj][i] + bv) * d2[i];
      }
    }
  }
  __syncthreads();
  flush_seg(Bb, Tbuf, dsum, 2 * H, 128);
}

// ---------------- edge kernel B: MFMA version (unchanged, validated) ----------------
__global__ __launch_bounds__(256, 1)
void k_edge_f_mfma(const float* __restrict__ edge_attr,
                   const float* __restrict__ sphe, const float* __restrict__ tors,
                   const ushort_t* __restrict__ wfT_hi, const ushort_t* __restrict__ wfT_lo,
                   const ushort_t* __restrict__ wcatT,
                   const ushort_t* __restrict__ wspheT, const ushort_t* __restrict__ wtorsT,
                   const float* __restrict__ bf, const float* __restrict__ bcat_f,
                   float* __restrict__ out_fji) {
  __shared__ __align__(16) ushort_t SH[64 * 256];
  __shared__ __align__(16) ushort_t SpheL[64 * 32];
  __shared__ __align__(16) ushort_t TorsL[64 * 32];
  ushort_t* AhiL = SH;
  ushort_t* AloL = SH + 8192;

  int tid = threadIdx.x;
  int e0  = blockIdx.x * 64;

  {
    int r = tid >> 2, qq = tid & 3;
    const float* src = edge_attr + (size_t)(e0 + r) * H + qq * 32;
    u32 swz = (u32)((r & 7) << 4);
    #pragma unroll
    for (int j = 0; j < 8; ++j) {
      float4 x = *(const float4*)(src + j * 4);
      ushort_t h0 = f2bf(x.x), h1 = f2bf(x.y), h2 = f2bf(x.z), h3 = f2bf(x.w);
      union { ushort_t s[4]; u64 u; } P;
      u32 off = ((u32)(r * 256 + (qq * 32 + j * 4) * 2)) ^ swz;
      P.s[0] = h0; P.s[1] = h1; P.s[2] = h2; P.s[3] = h3;
      *(u64*)((char*)AhiL + off) = P.u;
      P.s[0] = f2bf(x.x - bf2f(h0)); P.s[1] = f2bf(x.y - bf2f(h1));
      P.s[2] = f2bf(x.z - bf2f(h2)); P.s[3] = f2bf(x.w - bf2f(h3));
      *(u64*)((char*)AloL + off) = P.u;
    }
  }
  if (tid < 128) {
    int r = tid & 63;
    bool issp = tid < 64;
    ushort_t vals[32];
    #pragma unroll
    for (int i = 0; i < 32; ++i) vals[i] = 0;
    if (issp) {
      const float* sp = sphe + (size_t)(e0 + r) * SPH;
      #pragma unroll
      for (int i = 0; i < 12; ++i) vals[i] = f2bf(sp[i]);
    } else {
      const float* tp = tors + (size_t)(e0 + r) * TOR;
      #pragma unroll
      for (int i = 0; i < 6; ++i) vals[i] = f2bf(tp[i]);
    }
    ushort_t* dst = issp ? SpheL : TorsL;
    u32 swz = (u32)((r & 7) << 3);
    #pragma unroll
    for (int j = 0; j < 8; ++j) {
      union { ushort_t s[4]; u64 u; } P;
      P.s[0] = vals[j*4]; P.s[1] = vals[j*4+1]; P.s[2] = vals[j*4+2]; P.s[3] = vals[j*4+3];
      u32 off = ((u32)(r * 64 + j * 8)) ^ swz;
      *(u64*)((char*)dst + off) = P.u;
    }
  }
  __syncthreads();

  int lane = tid & 63;
  int w    = tid >> 6;
  int c    = lane & 15;
  int g    = lane >> 4;

  const int ntv[6] = {w, w + 4, 8 + w, 12 + w, 16 + w, 20 + w};

  f32x4 acc[4][6];
  #pragma unroll
  for (int mt = 0; mt < 4; ++mt)
    #pragma unroll
    for (int j = 0; j < 6; ++j) acc[mt][j] = (f32x4){0.f, 0.f, 0.f, 0.f};

  for (int t = 0; t < 4; ++t) {
    bf8 ah[4], al[4];
    #pragma unroll
    for (int mt = 0; mt < 4; ++mt) {
      int row = 16 * mt + c;
      u32 swz = (u32)((row & 7) << 4);
      u32 b0 = ((u32)(row * 256 + t * 64 + g * 8)) ^ swz;
      u32 b1 = ((u32)(row * 256 + t * 64 + 32 + g * 8)) ^ swz;
      ah[mt] = ld_lds_frag((const char*)AhiL, b0, b1);
      al[mt] = ld_lds_frag((const char*)AloL, b0, b1);
    }
    #pragma unroll
    for (int j = 0; j < 6; ++j) {
      int n = 16 * ntv[j] + c;
      bf8 bh = ld_g_frag(wfT_hi + n * 128 + t * 32 + g * 4);
      bf8 bl = ld_g_frag(wfT_lo + n * 128 + t * 32 + g * 4);
      #pragma unroll
      for (int mt = 0; mt < 4; ++mt) {
        acc[mt][j] = __builtin_amdgcn_mfma_f32_16x16x32_bf16(ah[mt], bh, acc[mt][j], 0, 0, 0);
        acc[mt][j] = __builtin_amdgcn_mfma_f32_16x16x32_bf16(al[mt], bh, acc[mt][j], 0, 0, 0);
        acc[mt][j] = __builtin_amdgcn_mfma_f32_16x16x32_bf16(ah[mt], bl, acc[mt][j], 0, 0, 0);
      }
    }
  }
  __syncthreads();

  bf8 spf[4], tof[4];
  #pragma unroll
  for (int mt = 0; mt < 4; ++mt) {
    int row = 16 * mt + c;
    u32 swz = (u32)((row & 7) << 3);
    u32 b0 = ((u32)(row * 64 + g * 8)) ^ swz;
    u32 b1 = ((u32)(row * 64 + 32 + g * 8)) ^ swz;
    spf[mt] = ld_lds_frag((const char*)SpheL, b0, b1);
    tof[mt] = ld_lds_frag((const char*)TorsL, b0, b1);
  }

  float sf1[2][4][4];
  #pragma unroll
  for (int jj = 0; jj < 2; ++jj) {
    float bv = bf[16 * ntv[jj] + c];
    #pragma unroll
    for (int mt = 0; mt < 4; ++mt)
      #pragma unroll
      for (int i = 0; i < 4; ++i)
        sf1[jj][mt][i] = sil(acc[mt][jj][i] + bv);
  }
  #pragma unroll
  for (int jj = 0; jj < 2; ++jj) {
    int j = 2 + jj;
    int nf = ntv[j] - 8;
    float bv = bf[16 * ntv[j] + c];
    bf8 wsf = ld_g_frag(wspheT + (16 * nf + c) * 32 + g * 4);
    #pragma unroll
    for (int mt = 0; mt < 4; ++mt) {
      f32x4 dz = (f32x4){0.f, 0.f, 0.f, 0.f};
      f32x4 d1 = __builtin_amdgcn_mfma_f32_16x16x32_bf16(spf[mt], wsf, dz, 0, 0, 0);
      #pragma unroll
      for (int i = 0; i < 4; ++i) {
        float y = sil(acc[mt][j][i] + bv) * d1[i];
        int row = 16 * mt + 4 * g + i;
        int col = 16 * nf + c;
        u32 off = ((u32)(row * 512 + col * 2)) ^ ((u32)((row & 7) << 4));
        *(ushort_t*)((char*)SH + off) = f2bf(y);
      }
    }
  }
  #pragma unroll
  for (int jj = 0; jj < 2; ++jj) {
    int j = 4 + jj;
    int nf = ntv[j] - 16;
    float bv = bf[16 * ntv[j] + c];
    bf8 wtf = ld_g_frag(wtorsT + (16 * nf + c) * 32 + g * 4);
    #pragma unroll
    for (int mt = 0; mt < 4; ++mt) {
      f32x4 dz = (f32x4){0.f, 0.f, 0.f, 0.f};
      f32x4 d2 = __builtin_amdgcn_mfma_f32_16x16x32_bf16(tof[mt], wtf, dz, 0, 0, 0);
      #pragma unroll
      for (int i = 0; i < 4; ++i) {
        float y = sil(acc[mt][j][i] + bv) * d2[i];
        int row = 16 * mt + 4 * g + i;
        int col = 128 + 16 * nf + c;
        u32 off = ((u32)(row * 512 + col * 2)) ^ ((u32)((row & 7) << 4));
        *(ushort_t*)((char*)SH + off) = f2bf(y);
      }
    }
  }
  __syncthreads();

  f32x4 acc2[4][2];
  #pragma unroll
  for (int mt = 0; mt < 4; ++mt) { acc2[mt][0] = (f32x4){0.f,0.f,0.f,0.f}; acc2[mt][1] = (f32x4){0.f,0.f,0.f,0.f}; }
  const int nt2[2] = {w, w + 4};
  for (int u = 0; u < 8; ++u) {
    bf8 yf[4];
    #pragma unroll
    for (int mt = 0; mt < 4; ++mt) {
      int row = 16 * mt + c;
      u32 swz = (u32)((row & 7) << 4);
      u32 b0 = ((u32)(row * 512 + u * 64 + g * 8)) ^ swz;
      u32 b1 = ((u32)(row * 512 + u * 64 + 32 + g * 8)) ^ swz;
      yf[mt] = ld_lds_frag((const char*)SH, b0, b1);
    }
    #pragma unroll
    for (int jj = 0; jj < 2; ++jj) {
      bf8 bfr = ld_g_frag(wcatT + (16 * nt2[jj] + c) * 256 + u * 32 + g * 4);
      #pragma unroll
      for (int mt = 0; mt < 4; ++mt)
        acc2[mt][jj] = __builtin_amdgcn_mfma_f32_16x16x32_bf16(yf[mt], bfr, acc2[mt][jj], 0, 0, 0);
    }
  }

  #pragma unroll
  for (int jj = 0; jj < 2; ++jj) {
    float bc = bcat_f[16 * nt2[jj] + c];
    #pragma unroll
    for (int mt = 0; mt < 4; ++mt) {
      #pragma unroll
      for (int i = 0; i < 4; ++i) {
        int row = 16 * mt + 4 * g + i;
        float v = sf1[jj][mt][i] + sil(acc2[mt][jj][i] + bc);
        out_fji[(size_t)(e0 + row) * H + 16 * nt2[jj] + c] = v;
      }
    }
  }
}

// ---------------- d_msg = dsum @ Wcat_msg ----------------
__global__ __launch_bounds__(256, 2)
void k_dmsg(const float* __restrict__ dsum, const float* __restrict__ Wcat_msg,
            float* __restrict__ d_msg) {
  __shared__ float X[64 * 260];
  int tid = threadIdx.x;
  int r0 = blockIdx.x * 64;
  for (int idx = tid; idx < 64 * 64; idx += 256) {
    int r = idx >> 6, seg = idx & 63;
    int row = r0 + r;
    float4 val = make_float4(0.f, 0.f, 0.f, 0.f);
    if (row < NT) val = *(const float4*)(dsum + (size_t)row * 2 * H + seg * 4);
    *(float4*)(X + r * 260 + seg * 4) = val;
  }
  __syncthreads();
  int lane = tid & 63, wave = tid >> 6;
  int c0 = __builtin_amdgcn_readfirstlane(wave * 32);
  float acc[32];
  #pragma unroll
  for (int j = 0; j < 32; ++j) acc[j] = 0.f;
  kloop32<256>(Wcat_msg + c0, H, X + lane * 260, acc);
  int row = r0 + lane;
  if (row < NT) {
    #pragma unroll
    for (int j4 = 0; j4 < 8; ++j4) {
      float4 o4 = make_float4(acc[j4*4], acc[j4*4+1], acc[j4*4+2], acc[j4*4+3]);
      *(float4*)(d_msg + (size_t)row * H + c0 + j4 * 4) = o4;
    }
  }
}

// ---------------- final ----------------
__global__ __launch_bounds__(256, 2)
void k_final(const float* __restrict__ s_msg, const float* __restrict__ x_t,
             const float* __restrict__ d_msg,
             const float* __restrict__ Wo_msg, const float* __restrict__ bo_msg,
             const float* __restrict__ Wfinal, const float* __restrict__ bfinal,
             float* __restrict__ out_ht) {
  __shared__ float SM[64 * TS];
  __shared__ float XT[64 * TS];
  int tid = threadIdx.x;
  int r0 = blockIdx.x * 64;
  for (int idx = tid; idx < 64 * 32; idx += 256) {
    int r = idx >> 5, seg = idx & 31;
    int row = r0 + r;
    float4 v1 = make_float4(0.f, 0.f, 0.f, 0.f), v2 = v1;
    if (row < NT) {
      v1 = *(const float4*)(s_msg + (size_t)row * H + seg * 4);
      v2 = *(const float4*)(x_t   + (size_t)row * H + seg * 4);
    }
    *(float4*)(SM + r * TS + seg * 4) = v1;
    *(float4*)(XT + r * TS + seg * 4) = v2;
  }
  __syncthreads();
  int lane = tid & 63, wave = tid >> 6;
  int c0 = __builtin_amdgcn_readfirstlane(wave * 32);
  int row = r0 + lane;
  float acc1[32], acc2[32];
  #pragma unroll
  for (int j = 0; j < 32; ++j) { acc1[j] = bo_msg[c0 + j]; acc2[j] = bo_msg[H + c0 + j]; }
  kloop32x2<128>(Wo_msg + c0, Wo_msg + H + c0, 2 * H, SM + lane * TS, acc1, acc2);
  float z[32];
  if (row < NT) {
    #pragma unroll
    for (int j4 = 0; j4 < 8; ++j4) {
      float4 dm = *(const float4*)(d_msg + (size_t)row * H + c0 + j4 * 4);
      z[j4*4]   = acc1[j4*4]   + acc2[j4*4]   * dm.x;
      z[j4*4+1] = acc1[j4*4+1] + acc2[j4*4+1] * dm.y;
      z[j4*4+2] = acc1[j4*4+2] + acc2[j4*4+2] * dm.z;
      z[j4*4+3] = acc1[j4*4+3] + acc2[j4*4+3] * dm.w;
    }
  } else {
    #pragma unroll
    for (int j = 0; j < 32; ++j) z[j] = 0.f;
  }
  __syncthreads();
  #pragma unroll
  for (int j4 = 0; j4 < 8; ++j4) {
    float4 o4 = make_float4(z[j4*4], z[j4*4+1], z[j4*4+2], z[j4*4+3]);
    *(float4*)(SM + lane * TS + c0 + j4 * 4) = o4;
  }
  __syncthreads();
  float acc[32];
  #pragma unroll
  for (int j = 0; j < 32; ++j) acc[j] = bfinal[c0 + j];
  kloop32<128>(Wfinal + c0, H, XT + lane * TS, acc);
  kloop32<128>(Wfinal + H * H + c0, H, SM + lane * TS, acc);
  if (row < NT) {
    #pragma unroll
    for (int j4 = 0; j4 < 8; ++j4) {
      float4 o4 = make_float4(sil(acc[j4*4]), sil(acc[j4*4+1]), sil(acc[j4*4+2]), sil(acc[j4*4+3]));
      *(float4*)(out_ht + (size_t)row * H + c0 + j4 * 4) = o4;
    }
  }
}

extern "C" void kernel_launch(void* const* d_in, const int* in_sizes, int n_in,
                              void* d_out, int out_size, void* d_ws, size_t ws_size,
                              hipStream_t stream) {
  const float* x_s       = (const float*)d_in[0];
  const float* x_t       = (const float*)d_in[1];
  const int*   ei        = (const int*)  d_in[2];
  const float* edge_attr = (const float*)d_in[3];
  const float* sphe      = (const float*)d_in[4];
  const float* tors      = (const float*)d_in[5];
  const float* dist      = (const float*)d_in[6];
  const float* Ws1       = (const float*)d_in[7];
  const float* Ws2       = (const float*)d_in[8];
  const float* Wt1       = (const float*)d_in[9];
  const float* Wt2       = (const float*)d_in[10];
  const float* Wq        = (const float*)d_in[11];
  const float* bq        = (const float*)d_in[12];
  const float* Wk        = (const float*)d_in[13];
  const float* bk        = (const float*)d_in[14];
  const float* Wv        = (const float*)d_in[15];
  const float* bv        = (const float*)d_in[16];
  const float* Wdk       = (const float*)d_in[17];
  const float* bdk       = (const float*)d_in[18];
  const float* Wdv       = (const float*)d_in[19];
  const float* bdv       = (const float*)d_in[20];
  const float* Wo_att    = (const float*)d_in[21];
  const float* bo_att    = (const float*)d_in[22];
  const float* Ws_msg    = (const float*)d_in[23];
  const float* bs_msg    = (const float*)d_in[24];
  const float* Wcat_msg  = (const float*)d_in[25];
  const float* Wo_msg    = (const float*)d_in[26];
  const float* bo_msg    = (const float*)d_in[27];
  const float* Wfinal    = (const float*)d_in[28];
  const float* bfinal    = (const float*)d_in[29];
  const float* Wf        = (const float*)d_in[30];
  const float* bf        = (const float*)d_in[31];
  const float* Wcat_f    = (const float*)d_in[32];
  const float* bcat_f    = (const float*)d_in[33];

  float* ws = (float*)d_ws;
  float* qbuf  = ws;                         // NT*H
  float* kbuf  = qbuf  + (size_t)NT * H;     // NS*H
  float* vbuf  = kbuf  + (size_t)NS * H;     // NS*H
  float* smsg  = vbuf  + (size_t)NS * H;     // NT*H
  float* dsum  = smsg  + (size_t)NT * H;     // NT*2H
  float* dmsg  = dsum  + (size_t)NT * 2 * H; // NT*H
  int*   deg    = (int*)(dmsg + (size_t)NT * H); // NT
  int*   cursor = deg + NT;                  // NT
  int*   perm   = cursor + NT;               // EDG
  ushort_t* wfT_hi  = (ushort_t*)(perm + EDG);   // 384*128
  ushort_t* wfT_lo  = wfT_hi + 384 * 128;
  ushort_t* wcatT   = wfT_lo + 384 * 128;        // 128*256
  ushort_t* wspheT  = wcatT + 128 * 256;         // 128*32
  ushort_t* wtorsT  = wspheT + 128 * 32;         // 128*32
  ushort_t* wdkT_hi = wtorsT + 128 * 32;         // 128*128 each below
  ushort_t* wdkT_lo = wdkT_hi + 128 * 128;
  ushort_t* wdvT_hi = wdkT_lo + 128 * 128;
  ushort_t* wdvT_lo = wdvT_hi + 128 * 128;
  ushort_t* woT_hi  = wdvT_lo + 128 * 128;
  ushort_t* woT_lo  = woT_hi + 128 * 128;
  ushort_t* wsmT_hi = woT_lo + 128 * 128;        // 256*128
  ushort_t* wsmT_lo = wsmT_hi + 256 * 128;

  float* out_ht  = (float*)d_out;
  float* out_fji = out_ht + (size_t)NT * H;

  hipMemsetAsync(smsg, 0, (size_t)NT * H * sizeof(float), stream);
  hipMemsetAsync(dsum, 0, (size_t)NT * 2 * H * sizeof(float), stream);
  hipMemsetAsync(deg, 0, (size_t)NT * sizeof(int), stream);

  k_hist<<<(EDG + 255) / 256, 256, 0, stream>>>(ei, deg);
  k_scan<<<1, 256, 0, stream>>>(deg, cursor);
  k_scatter<<<(EDG + 255) / 256, 256, 0, stream>>>(ei, cursor, perm);

  k_prepw<<<(384 * 128 + 255) / 256, 256, 0, stream>>>(
      Wf, Wcat_f, Ws1, Ws2, Wt1, Wt2, Wdk, Wdv, Wo_att, Ws_msg,
      wfT_hi, wfT_lo, wcatT, wspheT, wtorsT,
      wdkT_hi, wdkT_lo, wdvT_hi, wdvT_lo, woT_hi, woT_lo, wsmT_hi, wsmT_lo);

  int nblk = (NT + 63) / 64;
  k_gemm128<<<nblk, 256, 0, stream>>>(x_t, Wq, bq, qbuf, NT);
  k_gemm128<<<nblk, 256, 0, stream>>>(x_s, Wk, bk, kbuf, NS);
  k_gemm128<<<nblk, 256, 0, stream>>>(x_s, Wv, bv, vbuf, NS);

  k_edge_attn_mfma<<<EDG / 64, 256, 0, stream>>>(
      edge_attr, ei, perm, sphe, tors, dist, qbuf, kbuf, vbuf,
      wdkT_hi, wdkT_lo, wdvT_hi, wdvT_lo, woT_hi, woT_lo, wsmT_hi, wsmT_lo,
      wspheT, wtorsT, bdk, bdv, bo_att, bs_msg, smsg, dsum);

  k_edge_f_mfma<<<EDG / 64, 256, 0, stream>>>(edge_attr, sphe, tors,
                                              wfT_hi, wfT_lo, wcatT, wspheT, wtorsT,
                                              bf, bcat_f, out_fji);

  k_dmsg<<<nblk, 256, 0, stream>>>(dsum, Wcat_msg, dmsg);

  k_final<<<nblk, 256, 0, stream>>>(smsg, x_t, dmsg, Wo_msg, bo_msg,
                                    Wfinal, bfinal, out_ht);
}